// Round 6
// baseline (2962.029 us; speedup 1.0000x reference)
//
#include <hip/hip_runtime.h>
#include <hip/hip_fp16.h>

typedef _Float16 f16x2 __attribute__((ext_vector_type(2)));
typedef _Float16 half8 __attribute__((ext_vector_type(8)));
typedef float    f32x4 __attribute__((ext_vector_type(4)));

#define TS  512
#define HID 256
#define G3  768
#define EMB 128

__device__ __forceinline__ float sigmoidf_(float x){ return 1.0f/(1.0f+__expf(-x)); }
__device__ __forceinline__ float tanhf_(float x){
  float e = __expf(-2.0f*fabsf(x));
  float t = (1.0f-e)/(1.0f+e);
  return copysignf(t,x);
}

// K1: xi0[t][j] = bih0[j] + sum_k Wih0[j][k] * emb[x[t,511]][k]
__global__ __launch_bounds__(256) void xi0_kernel(const int* __restrict__ x,
    const float* __restrict__ emb_tab, const float* __restrict__ Wih0,
    const float* __restrict__ bih0, float* __restrict__ xi0)
{
  __shared__ float embs[8][EMB];
  __shared__ int idx8[8];
  int tid = threadIdx.x;
  int t0  = blockIdx.x * 8;
  if (tid < 8) idx8[tid] = x[(t0 + tid)*512 + 511];
  __syncthreads();
  for (int i = tid; i < 8*EMB; i += 256){
    int q = i >> 7, r = i & 127;
    embs[q][r] = emb_tab[(long)idx8[q]*EMB + r];
  }
  __syncthreads();
  for (int g = 0; g < 3; g++){
    int j = g*256 + tid;
    float b = bih0[j];
    float acc[8];
    #pragma unroll
    for (int u=0;u<8;u++) acc[u]=b;
    const float4* wrow = (const float4*)(Wih0 + (long)j*EMB);
    #pragma unroll 8
    for (int m=0;m<EMB/4;m++){
      float4 w = wrow[m];
      #pragma unroll
      for (int u=0;u<8;u++){
        acc[u] += w.x*embs[u][4*m+0] + w.y*embs[u][4*m+1]
                + w.z*embs[u][4*m+2] + w.w*embs[u][4*m+3];
      }
    }
    #pragma unroll
    for (int u=0;u<8;u++) xi0[(long)(t0+u)*G3 + j] = acc[u];
  }
}

// K3: xi1[t][j] = bih1[j] + sum_k Wih1[j][k] * h1[t][k]
__global__ __launch_bounds__(256) void xi1_kernel(const float* __restrict__ h1,
    const float* __restrict__ Wih1, const float* __restrict__ bih1,
    float* __restrict__ xi1)
{
  __shared__ float hs[8][HID];
  int tid = threadIdx.x;
  int t0  = blockIdx.x * 8;
  for (int i = tid; i < 8*HID; i += 256){
    int q = i >> 8, r = i & 255;
    hs[q][r] = h1[(long)(t0+q)*HID + r];
  }
  __syncthreads();
  for (int g = 0; g < 3; g++){
    int j = g*256 + tid;
    float b = bih1[j];
    float acc[8];
    #pragma unroll
    for (int u=0;u<8;u++) acc[u]=b;
    const float4* wrow = (const float4*)(Wih1 + (long)j*HID);
    #pragma unroll 4
    for (int m=0;m<HID/4;m++){
      float4 w = wrow[m];
      #pragma unroll
      for (int u=0;u<8;u++){
        acc[u] += w.x*hs[u][4*m+0] + w.y*hs[u][4*m+1]
                + w.z*hs[u][4*m+2] + w.w*hs[u][4*m+3];
      }
    }
    #pragma unroll
    for (int u=0;u<8;u++) xi1[(long)(t0+u)*G3 + j] = acc[u];
  }
}

// K2/K4: sequential GRU recurrence, MFMA formulation.
// gh_raw(768) = Whh(768x256) . h(256) per step, via mfma_f32_16x16x32_f16:
// 48 row-tiles x 8 k-blocks. 12 waves x 4 tiles (two passes of 2 tiles to
// keep live C at 4 regs). Weights live as 32 half8 SSA A-fragments per wave
// (128 reg-slots) consumed ONLY by mfma -> register allocator can place them
// in AGPRs (mfma reads A from AGPR directly; unlike fdot2 which is VGPR-only
// and forced scratch spills in rounds 1-5 at the hard 84-arch-VGPR budget).
// h broadcast: 16 ds_read_b128/wave/step (4 distinct addrs, 16-way bcast).
//
// Fragment layouts (cdna4_isa / m89-verified):
//   A[m][k]: m = lane&15, k = (lane>>4)*8 + j   (j = elem 0..7)
//   B[k][n]: n = lane&15, k = (lane>>4)*8 + j   (only n==0 nonzero here)
//   D[m][n]: n = lane&15, m = (lane>>4)*4 + reg
#define FOR_KB(X,P,T) X(P,T,0) X(P,T,1) X(P,T,2) X(P,T,3) X(P,T,4) X(P,T,5) X(P,T,6) X(P,T,7)
#define FOR_ALL(X) FOR_KB(X,0,0) FOR_KB(X,0,1) FOR_KB(X,1,0) FOR_KB(X,1,1)

__global__ __launch_bounds__(768)
void gru_rec_kernel(const float* __restrict__ Whh,
    const float* __restrict__ bhh, const float* __restrict__ xi,
    float* __restrict__ hout)
{
  __shared__ half8 hsh8[HID/8];            // h state, 256 f16
  __shared__ __align__(16) float gh[G3];   // raw Whh.h (no bias)
  int tid  = threadIdx.x;
  int wave = tid >> 6;
  int lane = tid & 63;
  int m15  = lane & 15;
  int kq   = lane >> 4;                    // 0..3

  // ---- one-time: load A-fragments (tile tau = wave + 12*(2P+T)) ----
#define ADECL(P,T,K) half8 a_##P##_##T##_##K;
  FOR_ALL(ADECL)
#define ALOAD(P,T,K) { \
    const float4* s_ = (const float4*)(Whh + (long)((wave + 12*(2*(P)+(T)))*16 + m15)*HID + (K)*32 + kq*8); \
    float4 u_ = s_[0], v_ = s_[1]; \
    a_##P##_##T##_##K = (half8){(_Float16)u_.x,(_Float16)u_.y,(_Float16)u_.z,(_Float16)u_.w, \
                                (_Float16)v_.x,(_Float16)v_.y,(_Float16)v_.z,(_Float16)v_.w}; }
  FOR_ALL(ALOAD)

  // elementwise-phase per-row constants (row = tid, tid<256)
  float bh_r=0.f, bh_z=0.f, bh_n=0.f, hprev=0.f;
  float xr=0.f, xz=0.f, xn=0.f;
  if (tid < HID){
    bh_r = bhh[tid]; bh_z = bhh[HID+tid]; bh_n = bhh[2*HID+tid];
    xr = xi[tid]; xz = xi[HID+tid]; xn = xi[2*HID+tid];
  }
  if (tid < HID/8){ half8 z8 = (half8)(_Float16)0; hsh8[tid] = z8; }
  __syncthreads();

  const half8 hzero = (half8)(_Float16)0;

  for (int t = 0; t < TS; t++){
    // prefetch next xi (overlaps with mfma phase)
    float xrn=0.f, xzn=0.f, xnn=0.f;
    if (tid < HID){
      int tn = (t+1 < TS) ? t+1 : t;
      const float* xirow = xi + (long)tn*G3;
      xrn = xirow[tid]; xzn = xirow[HID+tid]; xnn = xirow[2*HID+tid];
    }

    // ---- dot phase: two passes of 2 tiles ----
#define STEPKB(P,K) { \
      half8 hv_ = hsh8[(K)*4 + kq]; \
      half8 b_  = (m15 == 0) ? hv_ : hzero; \
      c0 = __builtin_amdgcn_mfma_f32_16x16x32_f16(a_##P##_0_##K, b_, c0, 0,0,0); \
      c1 = __builtin_amdgcn_mfma_f32_16x16x32_f16(a_##P##_1_##K, b_, c1, 0,0,0); }
#define PASS(P) { \
      f32x4 c0 = {0.f,0.f,0.f,0.f}, c1 = {0.f,0.f,0.f,0.f}; \
      FOR_KB(STEPKB_WRAP,P,unused) \
      if (m15 == 0){ \
        int r0_ = (wave + 12*(2*(P)+0))*16 + kq*4; \
        int r1_ = (wave + 12*(2*(P)+1))*16 + kq*4; \
        *(f32x4*)(gh + r0_) = c0; \
        *(f32x4*)(gh + r1_) = c1; } }
#define STEPKB_WRAP(P,T,K) STEPKB(P,K)
    PASS(0)
    PASS(1)
    __syncthreads();

    // ---- elementwise phase (rows 0..255 on waves 0..3) ----
    if (tid < HID){
      float r = sigmoidf_(xr + bh_r + gh[tid]);
      float z = sigmoidf_(xz + bh_z + gh[HID+tid]);
      float n = tanhf_(xn + r*(gh[2*HID+tid] + bh_n));
      float hnew = (1.0f - z)*n + z*hprev;
      hprev = hnew;
      hout[(long)t*HID + tid] = hnew;
      float partner = __shfl_xor(hnew, 1, 64);
      if ((tid & 1) == 0){
        f16x2 p; p.x = (_Float16)hnew; p.y = (_Float16)partner;
        ((f16x2*)hsh8)[tid >> 1] = p;
      }
      xr = xrn; xz = xzn; xn = xnn;
    }
    __syncthreads();
  }
}

// K5: logits[t][c] = b_out[c] + sum_i h2[t][i] * W_out[c][i]
__global__ __launch_bounds__(1024) void logits_kernel(const float* __restrict__ h2,
    const float* __restrict__ Wout, const float* __restrict__ bout,
    float* __restrict__ out)
{
  __shared__ __align__(16) float wsm[2*HID];
  __shared__ float bs[2];
  int tid = threadIdx.x;
  if (tid < 2*HID) wsm[tid] = Wout[tid];
  if (tid < 2)     bs[tid]  = bout[tid];
  __syncthreads();
  int t = tid >> 1, c = tid & 1;
  const float4* hr = (const float4*)(h2 + (long)t*HID);
  const float4* wr = (const float4*)(wsm + c*HID);
  float acc = bs[c];
  #pragma unroll 8
  for (int m=0;m<HID/4;m++){
    float4 h = hr[m]; float4 wv = wr[m];
    acc += h.x*wv.x + h.y*wv.y + h.z*wv.z + h.w*wv.w;
  }
  out[tid] = acc;
}

extern "C" void kernel_launch(void* const* d_in, const int* in_sizes, int n_in,
                              void* d_out, int out_size, void* d_ws, size_t ws_size,
                              hipStream_t stream)
{
  const int*   x    = (const int*)  d_in[0];
  const float* emb  = (const float*)d_in[1];
  const float* Wih0 = (const float*)d_in[2];
  const float* Whh0 = (const float*)d_in[3];
  const float* bih0 = (const float*)d_in[4];
  const float* bhh0 = (const float*)d_in[5];
  const float* Wih1 = (const float*)d_in[6];
  const float* Whh1 = (const float*)d_in[7];
  const float* bih1 = (const float*)d_in[8];
  const float* bhh1 = (const float*)d_in[9];
  const float* Wout = (const float*)d_in[10];
  const float* bout = (const float*)d_in[11];
  float* out = (float*)d_out;

  char* ws = (char*)d_ws;
  float* xi0 = (float*)(ws);                                  // 512*768 f32
  float* xi1 = (float*)(ws + (size_t)TS*G3*4);                // 512*768 f32
  float* h1  = (float*)(ws + (size_t)2*TS*G3*4);              // 512*256 f32
  float* h2  = (float*)(ws + (size_t)2*TS*G3*4 + (size_t)TS*HID*4);

  xi0_kernel   <<<64, 256, 0, stream>>>(x, emb, Wih0, bih0, xi0);
  gru_rec_kernel<<<1, 768, 0, stream>>>(Whh0, bhh0, xi0, h1);
  xi1_kernel   <<<64, 256, 0, stream>>>(h1, Wih1, bih1, xi1);
  gru_rec_kernel<<<1, 768, 0, stream>>>(Whh1, bhh1, xi1, h2);
  logits_kernel<<<1, 1024, 0, stream>>>(h2, Wout, bout, out);
}

// Round 7
// 1786.772 us; speedup vs baseline: 1.6578x; 1.6578x over previous
//
#include <hip/hip_runtime.h>
#include <hip/hip_fp16.h>

typedef _Float16 f16x2 __attribute__((ext_vector_type(2)));
typedef _Float16 half8 __attribute__((ext_vector_type(8)));

#define TS  512
#define HID 256
#define G3  768
#define EMB 128

__device__ __forceinline__ float sigmoidf_(float x){ return 1.0f/(1.0f+__expf(-x)); }
__device__ __forceinline__ float tanhf_(float x){
  float e = __expf(-2.0f*fabsf(x));
  float t = (1.0f-e)/(1.0f+e);
  return copysignf(t,x);
}

// K1: xi0[t][j] = bih0[j] + sum_k Wih0[j][k] * emb[x[t,511]][k]
__global__ __launch_bounds__(256) void xi0_kernel(const int* __restrict__ x,
    const float* __restrict__ emb_tab, const float* __restrict__ Wih0,
    const float* __restrict__ bih0, float* __restrict__ xi0)
{
  __shared__ float embs[8][EMB];
  __shared__ int idx8[8];
  int tid = threadIdx.x;
  int t0  = blockIdx.x * 8;
  if (tid < 8) idx8[tid] = x[(t0 + tid)*512 + 511];
  __syncthreads();
  for (int i = tid; i < 8*EMB; i += 256){
    int q = i >> 7, r = i & 127;
    embs[q][r] = emb_tab[(long)idx8[q]*EMB + r];
  }
  __syncthreads();
  for (int g = 0; g < 3; g++){
    int j = g*256 + tid;
    float b = bih0[j];
    float acc[8];
    #pragma unroll
    for (int u=0;u<8;u++) acc[u]=b;
    const float4* wrow = (const float4*)(Wih0 + (long)j*EMB);
    #pragma unroll 8
    for (int m=0;m<EMB/4;m++){
      float4 w = wrow[m];
      #pragma unroll
      for (int u=0;u<8;u++){
        acc[u] += w.x*embs[u][4*m+0] + w.y*embs[u][4*m+1]
                + w.z*embs[u][4*m+2] + w.w*embs[u][4*m+3];
      }
    }
    #pragma unroll
    for (int u=0;u<8;u++) xi0[(long)(t0+u)*G3 + j] = acc[u];
  }
}

// K3: xi1[t][j] = bih1[j] + sum_k Wih1[j][k] * h1[t][k]
__global__ __launch_bounds__(256) void xi1_kernel(const float* __restrict__ h1,
    const float* __restrict__ Wih1, const float* __restrict__ bih1,
    float* __restrict__ xi1)
{
  __shared__ float hs[8][HID];
  int tid = threadIdx.x;
  int t0  = blockIdx.x * 8;
  for (int i = tid; i < 8*HID; i += 256){
    int q = i >> 8, r = i & 255;
    hs[q][r] = h1[(long)(t0+q)*HID + r];
  }
  __syncthreads();
  for (int g = 0; g < 3; g++){
    int j = g*256 + tid;
    float b = bih1[j];
    float acc[8];
    #pragma unroll
    for (int u=0;u<8;u++) acc[u]=b;
    const float4* wrow = (const float4*)(Wih1 + (long)j*HID);
    #pragma unroll 4
    for (int m=0;m<HID/4;m++){
      float4 w = wrow[m];
      #pragma unroll
      for (int u=0;u<8;u++){
        acc[u] += w.x*hs[u][4*m+0] + w.y*hs[u][4*m+1]
                + w.z*hs[u][4*m+2] + w.w*hs[u][4*m+3];
      }
    }
    #pragma unroll
    for (int u=0;u<8;u++) xi1[(long)(t0+u)*G3 + j] = acc[u];
  }
}

// K2/K4: sequential GRU recurrence, group-split formulation.
// 1024 threads = 256 groups x 4. Group g owns output row g: gate rows
// {g, 256+g, 512+g}; thread q in the group covers k in [64q, 64q+64).
// Weights: 24 half8 SSA fragments = 96 VGPRs/thread (full matrix register-
// resident, f16). Why 1024 threads: with 768-thread blocks the backend's
// occupancy ladder is 3/6 waves/EU and its memory-bound heuristic always
// targeted 6 -> hard 84-VGPR budget -> weights spilled (rounds 1-6, VGPR=84
// every time). With 16 waves the ladder is 4 or 8 only; 4 waves/EU = 128-reg
// budget which fits 96 weights + ~25 working set. amdgpu_num_vgpr(128) makes
// the request explicit.
// h state: LDS, 4 chunks x (64 f16 + 16B pad) -> conflict-free 4-way
// broadcast ds_read_b128; double-buffered -> ONE barrier/step. Group-local
// reduction via 2x __shfl_xor (quad DPP, no LDS); leader (q==0) does gates.
#define W24(X) X(0,0) X(0,1) X(0,2) X(0,3) X(0,4) X(0,5) X(0,6) X(0,7) \
               X(1,0) X(1,1) X(1,2) X(1,3) X(1,4) X(1,5) X(1,6) X(1,7) \
               X(2,0) X(2,1) X(2,2) X(2,3) X(2,4) X(2,5) X(2,6) X(2,7)
#define C8(X) X(0) X(1) X(2) X(3) X(4) X(5) X(6) X(7)
#define SHUF(V,A,B) __builtin_shufflevector(V,V,A,B)

__global__ __launch_bounds__(1024, 4)
__attribute__((amdgpu_num_vgpr(128)))
void gru_rec_kernel(const float* __restrict__ Whh,
    const float* __restrict__ bhh, const float* __restrict__ xi,
    float* __restrict__ hout)
{
  // [2 buffers][4 chunks x 72 f16] ; chunk stride 72*2=144 B (16B pad)
  __shared__ __align__(16) _Float16 hls[2][4*72];
  int tid = threadIdx.x;
  int g   = tid >> 2;      // output row 0..255
  int q   = tid & 3;       // k-chunk 0..3

#define WDECL(R,C) half8 w##R##_##C;
  W24(WDECL)
#define WLOAD(R,C) { \
    const float4* p_ = (const float4*)(Whh + (long)((R)*HID + g)*HID + q*64 + (C)*8); \
    float4 u_ = p_[0], v_ = p_[1]; \
    w##R##_##C = (half8){(_Float16)u_.x,(_Float16)u_.y,(_Float16)u_.z,(_Float16)u_.w, \
                         (_Float16)v_.x,(_Float16)v_.y,(_Float16)v_.z,(_Float16)v_.w}; }
  W24(WLOAD)

  float bh_r=0.f, bh_z=0.f, bh_n=0.f, hprev=0.f;
  float xr=0.f, xz=0.f, xn=0.f;
  if (q == 0){
    bh_r = bhh[g]; bh_z = bhh[HID+g]; bh_n = bhh[2*HID+g];
    xr = xi[g]; xz = xi[HID+g]; xn = xi[2*HID+g];
  }
  if (tid < 72){ ((half8*)hls)[tid] = (half8)(_Float16)0; }
  __syncthreads();

  for (int t = 0; t < TS; t++){
    // prefetch next xi (leaders only; hidden behind the dot phase)
    float xrn=0.f, xzn=0.f, xnn=0.f;
    if (q == 0 && t+1 < TS){
      const float* xp = xi + (long)(t+1)*G3;
      xrn = xp[g]; xzn = xp[HID+g]; xnn = xp[2*HID+g];
    }

    const _Float16* hp = &hls[t & 1][q*72];
    float a0 = 0.f, a1 = 0.f, a2 = 0.f;
#define DOTC(C) { half8 hv = *(const half8*)(hp + (C)*8); \
    a0 = __builtin_amdgcn_fdot2(SHUF(w0_##C,0,1), SHUF(hv,0,1), a0, false); \
    a0 = __builtin_amdgcn_fdot2(SHUF(w0_##C,2,3), SHUF(hv,2,3), a0, false); \
    a0 = __builtin_amdgcn_fdot2(SHUF(w0_##C,4,5), SHUF(hv,4,5), a0, false); \
    a0 = __builtin_amdgcn_fdot2(SHUF(w0_##C,6,7), SHUF(hv,6,7), a0, false); \
    a1 = __builtin_amdgcn_fdot2(SHUF(w1_##C,0,1), SHUF(hv,0,1), a1, false); \
    a1 = __builtin_amdgcn_fdot2(SHUF(w1_##C,2,3), SHUF(hv,2,3), a1, false); \
    a1 = __builtin_amdgcn_fdot2(SHUF(w1_##C,4,5), SHUF(hv,4,5), a1, false); \
    a1 = __builtin_amdgcn_fdot2(SHUF(w1_##C,6,7), SHUF(hv,6,7), a1, false); \
    a2 = __builtin_amdgcn_fdot2(SHUF(w2_##C,0,1), SHUF(hv,0,1), a2, false); \
    a2 = __builtin_amdgcn_fdot2(SHUF(w2_##C,2,3), SHUF(hv,2,3), a2, false); \
    a2 = __builtin_amdgcn_fdot2(SHUF(w2_##C,4,5), SHUF(hv,4,5), a2, false); \
    a2 = __builtin_amdgcn_fdot2(SHUF(w2_##C,6,7), SHUF(hv,6,7), a2, false); }
    C8(DOTC)

    // quad reduction (lanes 4g..4g+3 are in the same wave)
    a0 += __shfl_xor(a0, 1, 64); a0 += __shfl_xor(a0, 2, 64);
    a1 += __shfl_xor(a1, 1, 64); a1 += __shfl_xor(a1, 2, 64);
    a2 += __shfl_xor(a2, 1, 64); a2 += __shfl_xor(a2, 2, 64);

    if (q == 0){
      float r = sigmoidf_(xr + bh_r + a0);
      float z = sigmoidf_(xz + bh_z + a1);
      float n = tanhf_(xn + r*(a2 + bh_n));
      float hnew = (1.0f - z)*n + z*hprev;
      hprev = hnew;
      hout[(long)t*HID + g] = hnew;
      hls[(t+1) & 1][((g>>6)*72) + (g & 63)] = (_Float16)hnew;
      xr = xrn; xz = xzn; xn = xnn;
    }
    __syncthreads();
  }
}

// K5: logits[t][c] = b_out[c] + sum_i h2[t][i] * W_out[c][i]
__global__ __launch_bounds__(1024) void logits_kernel(const float* __restrict__ h2,
    const float* __restrict__ Wout, const float* __restrict__ bout,
    float* __restrict__ out)
{
  __shared__ __align__(16) float wsm[2*HID];
  __shared__ float bs[2];
  int tid = threadIdx.x;
  if (tid < 2*HID) wsm[tid] = Wout[tid];
  if (tid < 2)     bs[tid]  = bout[tid];
  __syncthreads();
  int t = tid >> 1, c = tid & 1;
  const float4* hr = (const float4*)(h2 + (long)t*HID);
  const float4* wr = (const float4*)(wsm + c*HID);
  float acc = bs[c];
  #pragma unroll 8
  for (int m=0;m<HID/4;m++){
    float4 h = hr[m]; float4 wv = wr[m];
    acc += h.x*wv.x + h.y*wv.y + h.z*wv.z + h.w*wv.w;
  }
  out[tid] = acc;
}

extern "C" void kernel_launch(void* const* d_in, const int* in_sizes, int n_in,
                              void* d_out, int out_size, void* d_ws, size_t ws_size,
                              hipStream_t stream)
{
  const int*   x    = (const int*)  d_in[0];
  const float* emb  = (const float*)d_in[1];
  const float* Wih0 = (const float*)d_in[2];
  const float* Whh0 = (const float*)d_in[3];
  const float* bih0 = (const float*)d_in[4];
  const float* bhh0 = (const float*)d_in[5];
  const float* Wih1 = (const float*)d_in[6];
  const float* Whh1 = (const float*)d_in[7];
  const float* bih1 = (const float*)d_in[8];
  const float* bhh1 = (const float*)d_in[9];
  const float* Wout = (const float*)d_in[10];
  const float* bout = (const float*)d_in[11];
  float* out = (float*)d_out;

  char* ws = (char*)d_ws;
  float* xi0 = (float*)(ws);                                  // 512*768 f32
  float* xi1 = (float*)(ws + (size_t)TS*G3*4);                // 512*768 f32
  float* h1  = (float*)(ws + (size_t)2*TS*G3*4);              // 512*256 f32
  float* h2  = (float*)(ws + (size_t)2*TS*G3*4 + (size_t)TS*HID*4);

  xi0_kernel   <<<64, 256, 0, stream>>>(x, emb, Wih0, bih0, xi0);
  gru_rec_kernel<<<1, 1024, 0, stream>>>(Whh0, bhh0, xi0, h1);
  xi1_kernel   <<<64, 256, 0, stream>>>(h1, Wih1, bih1, xi1);
  gru_rec_kernel<<<1, 1024, 0, stream>>>(Whh1, bhh1, xi1, h2);
  logits_kernel<<<1, 1024, 0, stream>>>(h2, Wout, bout, out);
}

// Round 8
// 1660.688 us; speedup vs baseline: 1.7836x; 1.0759x over previous
//
#include <hip/hip_runtime.h>
#include <hip/hip_fp16.h>

typedef _Float16 f16x2 __attribute__((ext_vector_type(2)));
typedef _Float16 half8 __attribute__((ext_vector_type(8)));

#define TS  512
#define HID 256
#define G3  768
#define EMB 128

__device__ __forceinline__ float sigmoidf_(float x){ return 1.0f/(1.0f+__expf(-x)); }
__device__ __forceinline__ float tanhf_(float x){
  float e = __expf(-2.0f*fabsf(x));
  float t = (1.0f-e)/(1.0f+e);
  return copysignf(t,x);
}

// K1: xi0[t][j] = bih0[j] + sum_k Wih0[j][k] * emb[x[t,511]][k]
__global__ __launch_bounds__(256) void xi0_kernel(const int* __restrict__ x,
    const float* __restrict__ emb_tab, const float* __restrict__ Wih0,
    const float* __restrict__ bih0, float* __restrict__ xi0)
{
  __shared__ float embs[8][EMB];
  __shared__ int idx8[8];
  int tid = threadIdx.x;
  int t0  = blockIdx.x * 8;
  if (tid < 8) idx8[tid] = x[(t0 + tid)*512 + 511];
  __syncthreads();
  for (int i = tid; i < 8*EMB; i += 256){
    int q = i >> 7, r = i & 127;
    embs[q][r] = emb_tab[(long)idx8[q]*EMB + r];
  }
  __syncthreads();
  for (int g = 0; g < 3; g++){
    int j = g*256 + tid;
    float b = bih0[j];
    float acc[8];
    #pragma unroll
    for (int u=0;u<8;u++) acc[u]=b;
    const float4* wrow = (const float4*)(Wih0 + (long)j*EMB);
    #pragma unroll 8
    for (int m=0;m<EMB/4;m++){
      float4 w = wrow[m];
      #pragma unroll
      for (int u=0;u<8;u++){
        acc[u] += w.x*embs[u][4*m+0] + w.y*embs[u][4*m+1]
                + w.z*embs[u][4*m+2] + w.w*embs[u][4*m+3];
      }
    }
    #pragma unroll
    for (int u=0;u<8;u++) xi0[(long)(t0+u)*G3 + j] = acc[u];
  }
}

// K3: xi1[t][j] = bih1[j] + sum_k Wih1[j][k] * h1[t][k]
__global__ __launch_bounds__(256) void xi1_kernel(const float* __restrict__ h1,
    const float* __restrict__ Wih1, const float* __restrict__ bih1,
    float* __restrict__ xi1)
{
  __shared__ float hs[8][HID];
  int tid = threadIdx.x;
  int t0  = blockIdx.x * 8;
  for (int i = tid; i < 8*HID; i += 256){
    int q = i >> 8, r = i & 255;
    hs[q][r] = h1[(long)(t0+q)*HID + r];
  }
  __syncthreads();
  for (int g = 0; g < 3; g++){
    int j = g*256 + tid;
    float b = bih1[j];
    float acc[8];
    #pragma unroll
    for (int u=0;u<8;u++) acc[u]=b;
    const float4* wrow = (const float4*)(Wih1 + (long)j*HID);
    #pragma unroll 4
    for (int m=0;m<HID/4;m++){
      float4 w = wrow[m];
      #pragma unroll
      for (int u=0;u<8;u++){
        acc[u] += w.x*hs[u][4*m+0] + w.y*hs[u][4*m+1]
                + w.z*hs[u][4*m+2] + w.w*hs[u][4*m+3];
      }
    }
    #pragma unroll
    for (int u=0;u<8;u++) xi1[(long)(t0+u)*G3 + j] = acc[u];
  }
}

// K2/K4: sequential GRU recurrence, HYBRID weight residency.
// Measured law (rounds 1-7): the compiler grants each workgroup at most HALF
// the 512KB register file (768thr->84 VGPR, 1024thr->64 VGPR), immune to all
// occupancy attributes. The 384KB f16 weight matrix therefore CANNOT be fully
// register-resident. Split per row j (thread j, 768 threads):
//   cols [0,160):  20 half8 SSA chunks = 80 VGPRs  (240 KB block-wide)
//   cols [160,256): 96 f16 in LDS, row stride 104 f16 (208B = 13x16B; the
//     52-dword stride spreads 64 lanes evenly over all 32 banks -> only the
//     inherent 8cy/b128 cost)
// LDS budget: 768*208 + 512 (h) + 3072 (gh) = 163328 <= 163840.
// Per-step cost model: LDS weight reads 147KB @128B/cy ~ 1150cy + h
// broadcasts; VALU 128 fdot2 hides under it -> ~1900cy/step ~ 400us/layer.
#define W20(X) X(0) X(1) X(2) X(3) X(4) X(5) X(6) X(7) X(8) X(9) \
               X(10) X(11) X(12) X(13) X(14) X(15) X(16) X(17) X(18) X(19)
#define L12(X) X(0) X(1) X(2) X(3) X(4) X(5) X(6) X(7) X(8) X(9) X(10) X(11)
#define SHUF(V,A,B) __builtin_shufflevector(V,V,A,B)

__global__ __launch_bounds__(768)
void gru_rec_kernel(const float* __restrict__ Whh,
    const float* __restrict__ bhh, const float* __restrict__ xi,
    float* __restrict__ hout)
{
  __shared__ _Float16 lws[G3*104];        // LDS-resident weight cols [160,256)
  __shared__ half8 hsh8[HID/8];           // h state, 256 f16 (broadcast-read)
  __shared__ float gh[G3];
  int tid = threadIdx.x;                  // == output row j

  // ---- register-resident weights: cols [0,160) ----
#define WDECL(I) half8 w##I;
  W20(WDECL)
  {
    const float4* wrow = (const float4*)(Whh + (long)tid*HID);
#define WLOAD(I) { float4 u_ = wrow[2*(I)], v_ = wrow[2*(I)+1]; \
    w##I = (half8){(_Float16)u_.x,(_Float16)u_.y,(_Float16)u_.z,(_Float16)u_.w, \
                   (_Float16)v_.x,(_Float16)v_.y,(_Float16)v_.z,(_Float16)v_.w}; }
    W20(WLOAD)
  }
  // ---- LDS-resident weights: cols [160,256) ----
  {
    const float4* wrow = (const float4*)(Whh + (long)tid*HID + 160);
    half8* lrow = (half8*)(lws + tid*104);
#define LLOAD(I) { float4 u_ = wrow[2*(I)], v_ = wrow[2*(I)+1]; \
    lrow[I] = (half8){(_Float16)u_.x,(_Float16)u_.y,(_Float16)u_.z,(_Float16)u_.w, \
                      (_Float16)v_.x,(_Float16)v_.y,(_Float16)v_.z,(_Float16)v_.w}; }
    L12(LLOAD)
  }
  float breg = bhh[tid];

  if (tid < HID/8){ half8 z8 = (half8)(_Float16)0; hsh8[tid] = z8; }
  __syncthreads();

  float hprev = 0.0f;   // used by threads < 256 only

  // software-prefetched xi for step t
  float xiv_n = (tid < 512) ? xi[tid]       : 0.0f;
  float xnn   = (tid < HID) ? xi[512 + tid] : 0.0f;

  for (int t = 0; t < TS; t++){
    float xiv = xiv_n;
    float xnc = xnn;
    if (t + 1 < TS){
      xiv_n = (tid < 512) ? xi[(long)(t+1)*G3 + tid]       : 0.0f;
      xnn   = (tid < HID) ? xi[(long)(t+1)*G3 + 512 + tid] : 0.0f;
    }
    float acc0 = breg + xiv;   // j>=512 (n-gate): xiv==0, xn added after r*hn
    float acc1 = 0.0f;
    // register part: h chunks 0..19
#define RDOT(I) { half8 hv = hsh8[I]; \
    acc0 = __builtin_amdgcn_fdot2(SHUF(w##I,0,1), SHUF(hv,0,1), acc0, false); \
    acc1 = __builtin_amdgcn_fdot2(SHUF(w##I,2,3), SHUF(hv,2,3), acc1, false); \
    acc0 = __builtin_amdgcn_fdot2(SHUF(w##I,4,5), SHUF(hv,4,5), acc0, false); \
    acc1 = __builtin_amdgcn_fdot2(SHUF(w##I,6,7), SHUF(hv,6,7), acc1, false); }
    W20(RDOT)
    // LDS part: h chunks 20..31, weight chunks from lws
    {
      const half8* lrow = (const half8*)(lws + tid*104);
#define LDOT(I) { half8 hv = hsh8[20+(I)]; half8 wv = lrow[I]; \
    acc0 = __builtin_amdgcn_fdot2(SHUF(wv,0,1), SHUF(hv,0,1), acc0, false); \
    acc1 = __builtin_amdgcn_fdot2(SHUF(wv,2,3), SHUF(hv,2,3), acc1, false); \
    acc0 = __builtin_amdgcn_fdot2(SHUF(wv,4,5), SHUF(hv,4,5), acc0, false); \
    acc1 = __builtin_amdgcn_fdot2(SHUF(wv,6,7), SHUF(hv,6,7), acc1, false); }
      L12(LDOT)
    }
    gh[tid] = acc0 + acc1;
    __syncthreads();

    if (tid < HID){
      float r  = sigmoidf_(gh[tid]);
      float z  = sigmoidf_(gh[HID + tid]);
      float hn = gh[2*HID + tid];
      float n  = tanhf_(xnc + r*hn);
      float hnew = (1.0f - z)*n + z*hprev;
      hprev = hnew;
      hout[(long)t*HID + tid] = hnew;
      float partner = __shfl_xor(hnew, 1, 64);
      if ((tid & 1) == 0){
        f16x2 p; p.x = (_Float16)hnew; p.y = (_Float16)partner;
        ((f16x2*)hsh8)[tid >> 1] = p;
      }
    }
    __syncthreads();
  }
}

// K5: logits[t][c] = b_out[c] + sum_i h2[t][i] * W_out[c][i]
__global__ __launch_bounds__(1024) void logits_kernel(const float* __restrict__ h2,
    const float* __restrict__ Wout, const float* __restrict__ bout,
    float* __restrict__ out)
{
  __shared__ __align__(16) float wsm[2*HID];
  __shared__ float bs[2];
  int tid = threadIdx.x;
  if (tid < 2*HID) wsm[tid] = Wout[tid];
  if (tid < 2)     bs[tid]  = bout[tid];
  __syncthreads();
  int t = tid >> 1, c = tid & 1;
  const float4* hr = (const float4*)(h2 + (long)t*HID);
  const float4* wr = (const float4*)(wsm + c*HID);
  float acc = bs[c];
  #pragma unroll 8
  for (int m=0;m<HID/4;m++){
    float4 h = hr[m]; float4 wv = wr[m];
    acc += h.x*wv.x + h.y*wv.y + h.z*wv.z + h.w*wv.w;
  }
  out[tid] = acc;
}

extern "C" void kernel_launch(void* const* d_in, const int* in_sizes, int n_in,
                              void* d_out, int out_size, void* d_ws, size_t ws_size,
                              hipStream_t stream)
{
  const int*   x    = (const int*)  d_in[0];
  const float* emb  = (const float*)d_in[1];
  const float* Wih0 = (const float*)d_in[2];
  const float* Whh0 = (const float*)d_in[3];
  const float* bih0 = (const float*)d_in[4];
  const float* bhh0 = (const float*)d_in[5];
  const float* Wih1 = (const float*)d_in[6];
  const float* Whh1 = (const float*)d_in[7];
  const float* bih1 = (const float*)d_in[8];
  const float* bhh1 = (const float*)d_in[9];
  const float* Wout = (const float*)d_in[10];
  const float* bout = (const float*)d_in[11];
  float* out = (float*)d_out;

  char* ws = (char*)d_ws;
  float* xi0 = (float*)(ws);                                  // 512*768 f32
  float* xi1 = (float*)(ws + (size_t)TS*G3*4);                // 512*768 f32
  float* h1  = (float*)(ws + (size_t)2*TS*G3*4);              // 512*256 f32
  float* h2  = (float*)(ws + (size_t)2*TS*G3*4 + (size_t)TS*HID*4);

  xi0_kernel   <<<64, 256, 0, stream>>>(x, emb, Wih0, bih0, xi0);
  gru_rec_kernel<<<1, 768, 0, stream>>>(Whh0, bhh0, xi0, h1);
  xi1_kernel   <<<64, 256, 0, stream>>>(h1, Wih1, bih1, xi1);
  gru_rec_kernel<<<1, 768, 0, stream>>>(Whh1, bhh1, xi1, h2);
  logits_kernel<<<1, 1024, 0, stream>>>(h2, Wout, bout, out);
}

// Round 9
// 1535.503 us; speedup vs baseline: 1.9290x; 1.0815x over previous
//
#include <hip/hip_runtime.h>
#include <hip/hip_fp16.h>

typedef _Float16 f16x2 __attribute__((ext_vector_type(2)));
typedef _Float16 half8 __attribute__((ext_vector_type(8)));

#define TS  512
#define HID 256
#define G3  768
#define EMB 128

__device__ __forceinline__ float sigmoidf_(float x){ return 1.0f/(1.0f+__expf(-x)); }
__device__ __forceinline__ float tanhf_(float x){
  float e = __expf(-2.0f*fabsf(x));
  float t = (1.0f-e)/(1.0f+e);
  return copysignf(t,x);
}

// K1: xi0[t][j] = bih0[j] + sum_k Wih0[j][k] * emb[x[t,511]][k]
__global__ __launch_bounds__(256) void xi0_kernel(const int* __restrict__ x,
    const float* __restrict__ emb_tab, const float* __restrict__ Wih0,
    const float* __restrict__ bih0, float* __restrict__ xi0)
{
  __shared__ float embs[8][EMB];
  __shared__ int idx8[8];
  int tid = threadIdx.x;
  int t0  = blockIdx.x * 8;
  if (tid < 8) idx8[tid] = x[(t0 + tid)*512 + 511];
  __syncthreads();
  for (int i = tid; i < 8*EMB; i += 256){
    int q = i >> 7, r = i & 127;
    embs[q][r] = emb_tab[(long)idx8[q]*EMB + r];
  }
  __syncthreads();
  for (int g = 0; g < 3; g++){
    int j = g*256 + tid;
    float b = bih0[j];
    float acc[8];
    #pragma unroll
    for (int u=0;u<8;u++) acc[u]=b;
    const float4* wrow = (const float4*)(Wih0 + (long)j*EMB);
    #pragma unroll 8
    for (int m=0;m<EMB/4;m++){
      float4 w = wrow[m];
      #pragma unroll
      for (int u=0;u<8;u++){
        acc[u] += w.x*embs[u][4*m+0] + w.y*embs[u][4*m+1]
                + w.z*embs[u][4*m+2] + w.w*embs[u][4*m+3];
      }
    }
    #pragma unroll
    for (int u=0;u<8;u++) xi0[(long)(t0+u)*G3 + j] = acc[u];
  }
}

// K3: xi1[t][j] = bih1[j] + sum_k Wih1[j][k] * h1[t][k]
__global__ __launch_bounds__(256) void xi1_kernel(const float* __restrict__ h1,
    const float* __restrict__ Wih1, const float* __restrict__ bih1,
    float* __restrict__ xi1)
{
  __shared__ float hs[8][HID];
  int tid = threadIdx.x;
  int t0  = blockIdx.x * 8;
  for (int i = tid; i < 8*HID; i += 256){
    int q = i >> 8, r = i & 255;
    hs[q][r] = h1[(long)(t0+q)*HID + r];
  }
  __syncthreads();
  for (int g = 0; g < 3; g++){
    int j = g*256 + tid;
    float b = bih1[j];
    float acc[8];
    #pragma unroll
    for (int u=0;u<8;u++) acc[u]=b;
    const float4* wrow = (const float4*)(Wih1 + (long)j*HID);
    #pragma unroll 4
    for (int m=0;m<HID/4;m++){
      float4 w = wrow[m];
      #pragma unroll
      for (int u=0;u<8;u++){
        acc[u] += w.x*hs[u][4*m+0] + w.y*hs[u][4*m+1]
                + w.z*hs[u][4*m+2] + w.w*hs[u][4*m+3];
      }
    }
    #pragma unroll
    for (int u=0;u<8;u++) xi1[(long)(t0+u)*G3 + j] = acc[u];
  }
}

// K2/K4: sequential GRU recurrence, 4-way k-split.
// Round-8 lesson: per-thread FULL-row dots need 44 ds_read_b128/thread/step
// (528 DS wave-instrs/step ~ 3200cy -> 680us, the measured wall). Split k
// 4 ways instead: 768 threads = 192 quads x 4; thread (g,q) owns rows
// 4g..4g+3, cols [64q,64q+64) -> 32 half8 = 64 weight VGPRs (fits measured
// 84-VGPR/thread budget law WITH working set), and only 8 h-reads/thread/step
// (123 DS instrs/step total). Quad butterfly (shfl_xor 1,2) reduces the 4
// k-partials in-register; lane q writes raw gh[4g+q]; elementwise phase
// (threads<256) applies xi + biases + gates.
// h chunks stored at 144B stride: dword bank = (36q+4c)%32 -> the 4 quad
// addresses per instr hit disjoint bank quartets -> conflict-free.
#define C8(X) X(0) X(1) X(2) X(3) X(4) X(5) X(6) X(7)
#define W32(X) X(0,0) X(0,1) X(0,2) X(0,3) X(0,4) X(0,5) X(0,6) X(0,7) \
               X(1,0) X(1,1) X(1,2) X(1,3) X(1,4) X(1,5) X(1,6) X(1,7) \
               X(2,0) X(2,1) X(2,2) X(2,3) X(2,4) X(2,5) X(2,6) X(2,7) \
               X(3,0) X(3,1) X(3,2) X(3,3) X(3,4) X(3,5) X(3,6) X(3,7)
#define SHUF(V,A,B) __builtin_shufflevector(V,V,A,B)

__global__ __launch_bounds__(768)
void gru_rec_kernel(const float* __restrict__ Whh,
    const float* __restrict__ bhh, const float* __restrict__ xi,
    float* __restrict__ hout)
{
  __shared__ __align__(16) _Float16 hbuf[2][4*72];  // 4 chunks x (64 f16 + pad)
  __shared__ float gh[G3];
  int tid = threadIdx.x;
  int g   = tid >> 2;         // quad id 0..191  (rows 4g..4g+3)
  int q   = tid & 3;          // k-quarter: cols [64q, 64q+64)

  // ---- one-time: weights, rows 4g..4g+3 x cols [64q,64q+64) in registers ----
#define WDECL(I,C) half8 w##I##_##C;
  W32(WDECL)
#define WLOAD(I,C) { \
    const float4* p_ = (const float4*)(Whh + (long)(4*g+(I))*HID + 64*q + 8*(C)); \
    float4 u_ = p_[0], v_ = p_[1]; \
    w##I##_##C = (half8){(_Float16)u_.x,(_Float16)u_.y,(_Float16)u_.z,(_Float16)u_.w, \
                         (_Float16)v_.x,(_Float16)v_.y,(_Float16)v_.z,(_Float16)v_.w}; }
  W32(WLOAD)

  // elementwise-phase constants (thread j < 256 owns hidden unit j)
  float bh_r=0.f, bh_z=0.f, bh_n=0.f, hprev=0.f;
  float xr=0.f, xz=0.f, xn=0.f;
  if (tid < HID){
    bh_r = bhh[tid]; bh_z = bhh[HID+tid]; bh_n = bhh[2*HID+tid];
    xr = xi[tid]; xz = xi[HID+tid]; xn = xi[2*HID+tid];
  }
  if (tid < 72) ((half8*)hbuf)[tid] = (half8)(_Float16)0;   // zero both buffers
  __syncthreads();

  for (int t = 0; t < TS; t++){
    // prefetch next xi (hidden behind the dot phase)
    float xrn=0.f, xzn=0.f, xnn=0.f;
    if (tid < HID && t+1 < TS){
      const float* xp = xi + (long)(t+1)*G3;
      xrn = xp[tid]; xzn = xp[HID+tid]; xnn = xp[2*HID+tid];
    }

    // ---- dot phase: 8 h-chunk reads, 128 fdot2 ----
    const half8* hp = (const half8*)(&hbuf[t & 1][q*72]);
    float a0=0.f, a1=0.f, a2=0.f, a3=0.f;
#define DOTC(C) { half8 hv = hp[C]; \
    a0 = __builtin_amdgcn_fdot2(SHUF(w0_##C,0,1), SHUF(hv,0,1), a0, false); \
    a0 = __builtin_amdgcn_fdot2(SHUF(w0_##C,2,3), SHUF(hv,2,3), a0, false); \
    a0 = __builtin_amdgcn_fdot2(SHUF(w0_##C,4,5), SHUF(hv,4,5), a0, false); \
    a0 = __builtin_amdgcn_fdot2(SHUF(w0_##C,6,7), SHUF(hv,6,7), a0, false); \
    a1 = __builtin_amdgcn_fdot2(SHUF(w1_##C,0,1), SHUF(hv,0,1), a1, false); \
    a1 = __builtin_amdgcn_fdot2(SHUF(w1_##C,2,3), SHUF(hv,2,3), a1, false); \
    a1 = __builtin_amdgcn_fdot2(SHUF(w1_##C,4,5), SHUF(hv,4,5), a1, false); \
    a1 = __builtin_amdgcn_fdot2(SHUF(w1_##C,6,7), SHUF(hv,6,7), a1, false); \
    a2 = __builtin_amdgcn_fdot2(SHUF(w2_##C,0,1), SHUF(hv,0,1), a2, false); \
    a2 = __builtin_amdgcn_fdot2(SHUF(w2_##C,2,3), SHUF(hv,2,3), a2, false); \
    a2 = __builtin_amdgcn_fdot2(SHUF(w2_##C,4,5), SHUF(hv,4,5), a2, false); \
    a2 = __builtin_amdgcn_fdot2(SHUF(w2_##C,6,7), SHUF(hv,6,7), a2, false); \
    a3 = __builtin_amdgcn_fdot2(SHUF(w3_##C,0,1), SHUF(hv,0,1), a3, false); \
    a3 = __builtin_amdgcn_fdot2(SHUF(w3_##C,2,3), SHUF(hv,2,3), a3, false); \
    a3 = __builtin_amdgcn_fdot2(SHUF(w3_##C,4,5), SHUF(hv,4,5), a3, false); \
    a3 = __builtin_amdgcn_fdot2(SHUF(w3_##C,6,7), SHUF(hv,6,7), a3, false); }
    C8(DOTC)

    // quad butterfly: all 4 lanes end with full sums of all 4 rows
    a0 += __shfl_xor(a0, 1, 64); a1 += __shfl_xor(a1, 1, 64);
    a2 += __shfl_xor(a2, 1, 64); a3 += __shfl_xor(a3, 1, 64);
    a0 += __shfl_xor(a0, 2, 64); a1 += __shfl_xor(a1, 2, 64);
    a2 += __shfl_xor(a2, 2, 64); a3 += __shfl_xor(a3, 2, 64);
    float res = (q==0) ? a0 : (q==1) ? a1 : (q==2) ? a2 : a3;
    gh[4*g + q] = res;
    __syncthreads();

    // ---- elementwise phase: unit j = tid < 256 ----
    if (tid < HID){
      float r = sigmoidf_(xr + bh_r + gh[tid]);
      float z = sigmoidf_(xz + bh_z + gh[HID+tid]);
      float n = tanhf_(xn + r*(gh[2*HID+tid] + bh_n));
      float hnew = (1.0f - z)*n + z*hprev;
      hprev = hnew;
      hout[(long)t*HID + tid] = hnew;
      float partner = __shfl_xor(hnew, 1, 64);
      if ((tid & 1) == 0){
        f16x2 p; p.x = (_Float16)hnew; p.y = (_Float16)partner;
        *(f16x2*)(&hbuf[(t+1)&1][(tid>>6)*72 + (tid&63)]) = p;
      }
      xr = xrn; xz = xzn; xn = xnn;
    }
    __syncthreads();
  }
}

// K5: logits[t][c] = b_out[c] + sum_i h2[t][i] * W_out[c][i]
__global__ __launch_bounds__(1024) void logits_kernel(const float* __restrict__ h2,
    const float* __restrict__ Wout, const float* __restrict__ bout,
    float* __restrict__ out)
{
  __shared__ __align__(16) float wsm[2*HID];
  __shared__ float bs[2];
  int tid = threadIdx.x;
  if (tid < 2*HID) wsm[tid] = Wout[tid];
  if (tid < 2)     bs[tid]  = bout[tid];
  __syncthreads();
  int t = tid >> 1, c = tid & 1;
  const float4* hr = (const float4*)(h2 + (long)t*HID);
  const float4* wr = (const float4*)(wsm + c*HID);
  float acc = bs[c];
  #pragma unroll 8
  for (int m=0;m<HID/4;m++){
    float4 h = hr[m]; float4 wv = wr[m];
    acc += h.x*wv.x + h.y*wv.y + h.z*wv.z + h.w*wv.w;
  }
  out[tid] = acc;
}

extern "C" void kernel_launch(void* const* d_in, const int* in_sizes, int n_in,
                              void* d_out, int out_size, void* d_ws, size_t ws_size,
                              hipStream_t stream)
{
  const int*   x    = (const int*)  d_in[0];
  const float* emb  = (const float*)d_in[1];
  const float* Wih0 = (const float*)d_in[2];
  const float* Whh0 = (const float*)d_in[3];
  const float* bih0 = (const float*)d_in[4];
  const float* bhh0 = (const float*)d_in[5];
  const float* Wih1 = (const float*)d_in[6];
  const float* Whh1 = (const float*)d_in[7];
  const float* bih1 = (const float*)d_in[8];
  const float* bhh1 = (const float*)d_in[9];
  const float* Wout = (const float*)d_in[10];
  const float* bout = (const float*)d_in[11];
  float* out = (float*)d_out;

  char* ws = (char*)d_ws;
  float* xi0 = (float*)(ws);                                  // 512*768 f32
  float* xi1 = (float*)(ws + (size_t)TS*G3*4);                // 512*768 f32
  float* h1  = (float*)(ws + (size_t)2*TS*G3*4);              // 512*256 f32
  float* h2  = (float*)(ws + (size_t)2*TS*G3*4 + (size_t)TS*HID*4);

  xi0_kernel   <<<64, 256, 0, stream>>>(x, emb, Wih0, bih0, xi0);
  gru_rec_kernel<<<1, 768, 0, stream>>>(Whh0, bhh0, xi0, h1);
  xi1_kernel   <<<64, 256, 0, stream>>>(h1, Wih1, bih1, xi1);
  gru_rec_kernel<<<1, 768, 0, stream>>>(Whh1, bhh1, xi1, h2);
  logits_kernel<<<1, 1024, 0, stream>>>(h2, Wout, bout, out);
}

// Round 10
// 1215.121 us; speedup vs baseline: 2.4376x; 1.2637x over previous
//
#include <hip/hip_runtime.h>
#include <hip/hip_fp16.h>

typedef _Float16 f16x2 __attribute__((ext_vector_type(2)));
typedef _Float16 half8 __attribute__((ext_vector_type(8)));

#define TS  512
#define HID 256
#define G3  768
#define EMB 128
#define NB1 8
#define RPB 96   // rows per xi1-stage block

__device__ __forceinline__ float sigmoidf_(float x){ return 1.0f/(1.0f+__expf(-x)); }
__device__ __forceinline__ float tanhf_(float x){
  float e = __expf(-2.0f*fabsf(x));
  float t = (1.0f-e)/(1.0f+e);
  return copysignf(t,x);
}

// K1: xi0[t][j] = bih0[j] + sum_k Wih0[j][k] * emb[x[t,511]][k]
__global__ __launch_bounds__(256) void xi0_kernel(const int* __restrict__ x,
    const float* __restrict__ emb_tab, const float* __restrict__ Wih0,
    const float* __restrict__ bih0, float* __restrict__ xi0)
{
  __shared__ float embs[8][EMB];
  __shared__ int idx8[8];
  int tid = threadIdx.x;
  int t0  = blockIdx.x * 8;
  if (tid < 8) idx8[tid] = x[(t0 + tid)*512 + 511];
  __syncthreads();
  for (int i = tid; i < 8*EMB; i += 256){
    int q = i >> 7, r = i & 127;
    embs[q][r] = emb_tab[(long)idx8[q]*EMB + r];
  }
  __syncthreads();
  for (int g = 0; g < 3; g++){
    int j = g*256 + tid;
    float b = bih0[j];
    float acc[8];
    #pragma unroll
    for (int u=0;u<8;u++) acc[u]=b;
    const float4* wrow = (const float4*)(Wih0 + (long)j*EMB);
    #pragma unroll 8
    for (int m=0;m<EMB/4;m++){
      float4 w = wrow[m];
      #pragma unroll
      for (int u=0;u<8;u++){
        acc[u] += w.x*embs[u][4*m+0] + w.y*embs[u][4*m+1]
                + w.z*embs[u][4*m+2] + w.w*embs[u][4*m+3];
      }
    }
    #pragma unroll
    for (int u=0;u<8;u++) xi0[(long)(t0+u)*G3 + j] = acc[u];
  }
}

// ---------------- pipelined recurrence (1 kernel, 10 blocks) ----------------
// B0: layer-1 rec (round-9 structure), publishes h1[t] (f16) + flag0[t].
// B1..B8: xi1[t] = Wih1 . h1[t] + bih1, 96 rows each, weights streamed from
//         L2 (f32); publishes xi1 rows + atomicAdd(cnt1[t]).
// B9: layer-2 rec, per step polls cnt1[t]==8, loads xi1[t], writes h2 (f32).
// Handshake (cross-XCD safe): producer __syncthreads (vmcnt drain) ->
// tid0 __threadfence (L2 writeback) -> relaxed agent-atomic flag; consumer
// tid0 spins on agent-atomic -> __threadfence -> __syncthreads -> plain
// loads (data lines are cold per t: never cached stale on consumer XCD).

#define C8(X) X(0) X(1) X(2) X(3) X(4) X(5) X(6) X(7)
#define W32(X) X(0,0) X(0,1) X(0,2) X(0,3) X(0,4) X(0,5) X(0,6) X(0,7) \
               X(1,0) X(1,1) X(1,2) X(1,3) X(1,4) X(1,5) X(1,6) X(1,7) \
               X(2,0) X(2,1) X(2,2) X(2,3) X(2,4) X(2,5) X(2,6) X(2,7) \
               X(3,0) X(3,1) X(3,2) X(3,3) X(3,4) X(3,5) X(3,6) X(3,7)
#define SHUF(V,A,B) __builtin_shufflevector(V,V,A,B)

template<int MODE>  // 0 = producer (layer 1), 1 = consumer (layer 2)
__device__ __forceinline__ void rec_layer(const float* __restrict__ Whh,
    const float* __restrict__ bhh, const float* __restrict__ xi,
    _Float16* __restrict__ h16out, float* __restrict__ f32out,
    unsigned* __restrict__ flag0, unsigned* __restrict__ cnt1,
    _Float16 (*hbuf)[4*72], float* gh)
{
  int tid = threadIdx.x;
  int g   = tid >> 2;         // quad id 0..191  (rows 4g..4g+3)
  int q   = tid & 3;          // k-quarter: cols [64q, 64q+64)

#define WDECL(I,C) half8 w##I##_##C;
  W32(WDECL)
#define WLOAD(I,C) { \
    const float4* p_ = (const float4*)(Whh + (long)(4*g+(I))*HID + 64*q + 8*(C)); \
    float4 u_ = p_[0], v_ = p_[1]; \
    w##I##_##C = (half8){(_Float16)u_.x,(_Float16)u_.y,(_Float16)u_.z,(_Float16)u_.w, \
                         (_Float16)v_.x,(_Float16)v_.y,(_Float16)v_.z,(_Float16)v_.w}; }
  W32(WLOAD)

  float bh_r=0.f, bh_z=0.f, bh_n=0.f, hprev=0.f;
  float xr=0.f, xz=0.f, xn=0.f;
  if (tid < HID){
    bh_r = bhh[tid]; bh_z = bhh[HID+tid]; bh_n = bhh[2*HID+tid];
    if (MODE == 0){ xr = xi[tid]; xz = xi[HID+tid]; xn = xi[2*HID+tid]; }
  }
  if (tid < 72) ((half8*)hbuf)[tid] = (half8)(_Float16)0;
  __syncthreads();

  for (int t = 0; t < TS; t++){
    if (MODE == 1){
      if (tid == 0){
        while (__hip_atomic_load(&cnt1[t], __ATOMIC_RELAXED, __HIP_MEMORY_SCOPE_AGENT) < NB1)
          __builtin_amdgcn_s_sleep(1);
        __threadfence();
      }
      __syncthreads();
      if (tid < HID){
        const float* xp = xi + (long)t*G3;
        xr = xp[tid]; xz = xp[HID+tid]; xn = xp[2*HID+tid];
      }
    }
    float xrn=0.f, xzn=0.f, xnn=0.f;
    if (MODE == 0 && tid < HID && t+1 < TS){
      const float* xp = xi + (long)(t+1)*G3;
      xrn = xp[tid]; xzn = xp[HID+tid]; xnn = xp[2*HID+tid];
    }

    const half8* hp = (const half8*)(&hbuf[t & 1][q*72]);
    float a0=0.f, a1=0.f, a2=0.f, a3=0.f;
#define DOTC(C) { half8 hv = hp[C]; \
    a0 = __builtin_amdgcn_fdot2(SHUF(w0_##C,0,1), SHUF(hv,0,1), a0, false); \
    a0 = __builtin_amdgcn_fdot2(SHUF(w0_##C,2,3), SHUF(hv,2,3), a0, false); \
    a0 = __builtin_amdgcn_fdot2(SHUF(w0_##C,4,5), SHUF(hv,4,5), a0, false); \
    a0 = __builtin_amdgcn_fdot2(SHUF(w0_##C,6,7), SHUF(hv,6,7), a0, false); \
    a1 = __builtin_amdgcn_fdot2(SHUF(w1_##C,0,1), SHUF(hv,0,1), a1, false); \
    a1 = __builtin_amdgcn_fdot2(SHUF(w1_##C,2,3), SHUF(hv,2,3), a1, false); \
    a1 = __builtin_amdgcn_fdot2(SHUF(w1_##C,4,5), SHUF(hv,4,5), a1, false); \
    a1 = __builtin_amdgcn_fdot2(SHUF(w1_##C,6,7), SHUF(hv,6,7), a1, false); \
    a2 = __builtin_amdgcn_fdot2(SHUF(w2_##C,0,1), SHUF(hv,0,1), a2, false); \
    a2 = __builtin_amdgcn_fdot2(SHUF(w2_##C,2,3), SHUF(hv,2,3), a2, false); \
    a2 = __builtin_amdgcn_fdot2(SHUF(w2_##C,4,5), SHUF(hv,4,5), a2, false); \
    a2 = __builtin_amdgcn_fdot2(SHUF(w2_##C,6,7), SHUF(hv,6,7), a2, false); \
    a3 = __builtin_amdgcn_fdot2(SHUF(w3_##C,0,1), SHUF(hv,0,1), a3, false); \
    a3 = __builtin_amdgcn_fdot2(SHUF(w3_##C,2,3), SHUF(hv,2,3), a3, false); \
    a3 = __builtin_amdgcn_fdot2(SHUF(w3_##C,4,5), SHUF(hv,4,5), a3, false); \
    a3 = __builtin_amdgcn_fdot2(SHUF(w3_##C,6,7), SHUF(hv,6,7), a3, false); }
    C8(DOTC)

    a0 += __shfl_xor(a0, 1, 64); a1 += __shfl_xor(a1, 1, 64);
    a2 += __shfl_xor(a2, 1, 64); a3 += __shfl_xor(a3, 1, 64);
    a0 += __shfl_xor(a0, 2, 64); a1 += __shfl_xor(a1, 2, 64);
    a2 += __shfl_xor(a2, 2, 64); a3 += __shfl_xor(a3, 2, 64);
    float res = (q==0) ? a0 : (q==1) ? a1 : (q==2) ? a2 : a3;
    gh[4*g + q] = res;
    __syncthreads();

    if (tid < HID){
      float r = sigmoidf_(xr + bh_r + gh[tid]);
      float z = sigmoidf_(xz + bh_z + gh[HID+tid]);
      float n = tanhf_(xn + r*(gh[2*HID+tid] + bh_n));
      float hnew = (1.0f - z)*n + z*hprev;
      hprev = hnew;
      if (MODE == 1) f32out[(long)t*HID + tid] = hnew;
      float partner = __shfl_xor(hnew, 1, 64);
      if ((tid & 1) == 0){
        f16x2 p; p.x = (_Float16)hnew; p.y = (_Float16)partner;
        *(f16x2*)(&hbuf[(t+1)&1][(tid>>6)*72 + (tid&63)]) = p;
        if (MODE == 0) *(f16x2*)(h16out + (long)t*HID + tid) = p;
      }
      if (MODE == 0){ xr = xrn; xz = xzn; xn = xnn; }
    }
    __syncthreads();
    if (MODE == 0 && tid == 0){
      __threadfence();
      __hip_atomic_store(&flag0[t], 1u, __ATOMIC_RELEASE, __HIP_MEMORY_SCOPE_AGENT);
    }
  }
}

__device__ __forceinline__ void xi1_stage(const float* __restrict__ Wih1,
    const float* __restrict__ bih1, const _Float16* __restrict__ h16,
    float* __restrict__ xi1, unsigned* __restrict__ flag0,
    unsigned* __restrict__ cnt1, int slice)
{
  int tid = threadIdx.x;
  int r = tid >> 3, o = tid & 7;        // r 0..95, o 0..7: cols [32o,32o+32)
  int row = slice*RPB + r;
  const float4* wp = (const float4*)(Wih1 + (long)row*HID + o*32);
  float bias = bih1[row];

  for (int t = 0; t < TS; t++){
    if (tid == 0){
      while (__hip_atomic_load(&flag0[t], __ATOMIC_RELAXED, __HIP_MEMORY_SCOPE_AGENT) == 0u)
        __builtin_amdgcn_s_sleep(1);
      __threadfence();
    }
    __syncthreads();
    const half8* hp = (const half8*)(h16 + (long)t*HID + o*32);
    half8 h0 = hp[0], h1v = hp[1], h2v = hp[2], h3v = hp[3];
    float acc = 0.f;
#define B1DOT(HV,IA,IB) { float4 wa = wp[IA], wb = wp[IB]; \
    acc += wa.x*(float)HV[0] + wa.y*(float)HV[1] + wa.z*(float)HV[2] + wa.w*(float)HV[3] \
         + wb.x*(float)HV[4] + wb.y*(float)HV[5] + wb.z*(float)HV[6] + wb.w*(float)HV[7]; }
    B1DOT(h0,0,1) B1DOT(h1v,2,3) B1DOT(h2v,4,5) B1DOT(h3v,6,7)
    acc += __shfl_xor(acc, 1, 64);
    acc += __shfl_xor(acc, 2, 64);
    acc += __shfl_xor(acc, 4, 64);
    if (o == 0) xi1[(long)t*G3 + row] = acc + bias;
    __syncthreads();
    if (tid == 0){
      __threadfence();
      atomicAdd(&cnt1[t], 1u);
    }
  }
}

__global__ __launch_bounds__(768) void pipe_kernel(
    const float* __restrict__ Whh0, const float* __restrict__ bhh0,
    const float* __restrict__ xi0,
    const float* __restrict__ Wih1, const float* __restrict__ bih1,
    const float* __restrict__ Whh1, const float* __restrict__ bhh1,
    _Float16* __restrict__ h1f16, float* __restrict__ xi1,
    float* __restrict__ h2, unsigned* __restrict__ flag0,
    unsigned* __restrict__ cnt1)
{
  __shared__ __align__(16) _Float16 hbuf[2][4*72];
  __shared__ float gh[G3];
  int bid = blockIdx.x;
  if (bid == 0)
    rec_layer<0>(Whh0, bhh0, xi0, h1f16, nullptr, flag0, cnt1, hbuf, gh);
  else if (bid == 9)
    rec_layer<1>(Whh1, bhh1, xi1, nullptr, h2, flag0, cnt1, hbuf, gh);
  else
    xi1_stage(Wih1, bih1, h1f16, xi1, flag0, cnt1, bid - 1);
}

// K5: logits[t][c] = b_out[c] + sum_i h2[t][i] * W_out[c][i]
__global__ __launch_bounds__(1024) void logits_kernel(const float* __restrict__ h2,
    const float* __restrict__ Wout, const float* __restrict__ bout,
    float* __restrict__ out)
{
  __shared__ __align__(16) float wsm[2*HID];
  __shared__ float bs[2];
  int tid = threadIdx.x;
  if (tid < 2*HID) wsm[tid] = Wout[tid];
  if (tid < 2)     bs[tid]  = bout[tid];
  __syncthreads();
  int t = tid >> 1, c = tid & 1;
  const float4* hr = (const float4*)(h2 + (long)t*HID);
  const float4* wr = (const float4*)(wsm + c*HID);
  float acc = bs[c];
  #pragma unroll 8
  for (int m=0;m<HID/4;m++){
    float4 h = hr[m]; float4 wv = wr[m];
    acc += h.x*wv.x + h.y*wv.y + h.z*wv.z + h.w*wv.w;
  }
  out[tid] = acc;
}

extern "C" void kernel_launch(void* const* d_in, const int* in_sizes, int n_in,
                              void* d_out, int out_size, void* d_ws, size_t ws_size,
                              hipStream_t stream)
{
  const int*   x    = (const int*)  d_in[0];
  const float* emb  = (const float*)d_in[1];
  const float* Wih0 = (const float*)d_in[2];
  const float* Whh0 = (const float*)d_in[3];
  const float* bih0 = (const float*)d_in[4];
  const float* bhh0 = (const float*)d_in[5];
  const float* Wih1 = (const float*)d_in[6];
  const float* Whh1 = (const float*)d_in[7];
  const float* bih1 = (const float*)d_in[8];
  const float* bhh1 = (const float*)d_in[9];
  const float* Wout = (const float*)d_in[10];
  const float* bout = (const float*)d_in[11];
  float* out = (float*)d_out;

  char* ws = (char*)d_ws;
  float*     xi0   = (float*)(ws);                       // 512*768 f32 = 1.5 MB
  float*     xi1   = (float*)(ws + 1572864);             // 512*768 f32 = 1.5 MB
  _Float16*  h1f16 = (_Float16*)(ws + 3145728);          // 512*256 f16 = 256 KB
  float*     h2    = (float*)(ws + 3407872);             // 512*256 f32 = 512 KB
  unsigned*  flag0 = (unsigned*)(ws + 3932160);          // 512 u32
  unsigned*  cnt1  = (unsigned*)(ws + 3934208);          // 512 u32

  hipMemsetAsync(ws + 3932160, 0, 4096, stream);
  xi0_kernel<<<64, 256, 0, stream>>>(x, emb, Wih0, bih0, xi0);
  pipe_kernel<<<10, 768, 0, stream>>>(Whh0, bhh0, xi0, Wih1, bih1,
                                      Whh1, bhh1, h1f16, xi1, h2, flag0, cnt1);
  logits_kernel<<<1, 1024, 0, stream>>>(h2, Wout, bout, out);
}

// Round 11
// 1184.633 us; speedup vs baseline: 2.5004x; 1.0257x over previous
//
#include <hip/hip_runtime.h>
#include <hip/hip_fp16.h>

typedef _Float16 f16x2 __attribute__((ext_vector_type(2)));
typedef _Float16 half8 __attribute__((ext_vector_type(8)));

#define TS  512
#define HID 256
#define G3  768
#define EMB 128
#define NB1 8
#define RPB 96   // rows per xi1-stage block
#define CTL 767  // poller/publisher thread (no xi prefetch loads -> cheap fence)

__device__ __forceinline__ float sigmoidf_(float x){ return 1.0f/(1.0f+__expf(-x)); }
__device__ __forceinline__ float tanhf_(float x){
  float e = __expf(-2.0f*fabsf(x));
  float t = (1.0f-e)/(1.0f+e);
  return copysignf(t,x);
}

// K1: xi0[t][j] = bih0[j] + sum_k Wih0[j][k] * emb[x[t,511]][k]
__global__ __launch_bounds__(256) void xi0_kernel(const int* __restrict__ x,
    const float* __restrict__ emb_tab, const float* __restrict__ Wih0,
    const float* __restrict__ bih0, float* __restrict__ xi0)
{
  __shared__ float embs[8][EMB];
  __shared__ int idx8[8];
  int tid = threadIdx.x;
  int t0  = blockIdx.x * 8;
  if (tid < 8) idx8[tid] = x[(t0 + tid)*512 + 511];
  __syncthreads();
  for (int i = tid; i < 8*EMB; i += 256){
    int q = i >> 7, r = i & 127;
    embs[q][r] = emb_tab[(long)idx8[q]*EMB + r];
  }
  __syncthreads();
  for (int g = 0; g < 3; g++){
    int j = g*256 + tid;
    float b = bih0[j];
    float acc[8];
    #pragma unroll
    for (int u=0;u<8;u++) acc[u]=b;
    const float4* wrow = (const float4*)(Wih0 + (long)j*EMB);
    #pragma unroll 8
    for (int m=0;m<EMB/4;m++){
      float4 w = wrow[m];
      #pragma unroll
      for (int u=0;u<8;u++){
        acc[u] += w.x*embs[u][4*m+0] + w.y*embs[u][4*m+1]
                + w.z*embs[u][4*m+2] + w.w*embs[u][4*m+3];
      }
    }
    #pragma unroll
    for (int u=0;u<8;u++) xi0[(long)(t0+u)*G3 + j] = acc[u];
  }
}

// ---------------- pipelined recurrence (1 kernel, 10 blocks) ----------------
// Recurrence split (NEW, round 11): 768 threads; thread tid = (g,o), g=tid>>3,
// o=tid&7 owns rows 8g..8g+7 x cols [32o,32o+32) -> 32 half8 = 64 weight
// VGPRs + ~20 working = 84 = the measured hard budget -> NO spill (rounds
// 1-10 all spilled: any full-row or 4-way shape needs 128). Only 4
// ds_read_b128 of h per thread per step. 8-lane butterfly (select-send
// shfl_xor 1,2,4) leaves row tid's full dot on lane o -> gh[tid].
// h chunks at 80B stride: 8 b128 addrs/instr hit 8 disjoint bank quartets.
// B1..8: Wih1 slice as 16 f16 VGPRs (was: 98KB/step streamed from L2 ->
// 50MB/dispatch FETCH, round-10 counter). B9 hides handshake: poll
// cnt1[t+1] at top of step t, prefetch xi1[t+1] in elementwise phase.
#define SHUF(V,A,B) __builtin_shufflevector(V,V,A,B)
#define WR32(X) X(0,0) X(0,1) X(0,2) X(0,3) X(1,0) X(1,1) X(1,2) X(1,3) \
                X(2,0) X(2,1) X(2,2) X(2,3) X(3,0) X(3,1) X(3,2) X(3,3) \
                X(4,0) X(4,1) X(4,2) X(4,3) X(5,0) X(5,1) X(5,2) X(5,3) \
                X(6,0) X(6,1) X(6,2) X(6,3) X(7,0) X(7,1) X(7,2) X(7,3)

template<int MODE>  // 0 = producer (layer 1), 1 = consumer (layer 2)
__device__ __forceinline__ void rec_layer(const float* __restrict__ Whh,
    const float* __restrict__ bhh, const float* __restrict__ xi,
    _Float16* __restrict__ h16out, float* __restrict__ f32out,
    unsigned* __restrict__ flag0, unsigned* __restrict__ cnt1,
    _Float16 (*hbuf)[8*40], float* gh)
{
  int tid = threadIdx.x;
  int g   = tid >> 3;        // 0..95 : rows 8g..8g+7
  int o   = tid & 7;         // col chunk [32o, 32o+32)

#define WDECL(I,C) half8 w##I##_##C;
  WR32(WDECL)
#define WLOAD(I,C) { \
    const float4* p_ = (const float4*)(Whh + (long)(8*g+(I))*HID + 32*o + 8*(C)); \
    float4 u_ = p_[0], v_ = p_[1]; \
    w##I##_##C = (half8){(_Float16)u_.x,(_Float16)u_.y,(_Float16)u_.z,(_Float16)u_.w, \
                         (_Float16)v_.x,(_Float16)v_.y,(_Float16)v_.z,(_Float16)v_.w}; }
  WR32(WLOAD)

  float bh_r=0.f, bh_z=0.f, bh_n=0.f, hprev=0.f;
  float xr=0.f, xz=0.f, xn=0.f;
  if (tid < HID){
    bh_r = bhh[tid]; bh_z = bhh[HID+tid]; bh_n = bhh[2*HID+tid];
  }
  if (tid < 80) ((half8*)hbuf)[tid] = (half8)(_Float16)0;  // zero both buffers

  if (MODE == 1){
    if (tid == CTL){
      while (__hip_atomic_load(&cnt1[0], __ATOMIC_RELAXED, __HIP_MEMORY_SCOPE_AGENT) < NB1)
        __builtin_amdgcn_s_sleep(1);
      __threadfence();
    }
  }
  __syncthreads();
  if (tid < HID){  // xi for t=0 (MODE1: safe after cnt1[0] confirmed)
    xr = xi[tid]; xz = xi[HID+tid]; xn = xi[2*HID+tid];
  }

  for (int t = 0; t < TS; t++){
    // consumer: confirm step t+1's xi1 early; fence (cache inv) covers the
    // prefetch loads issued in this step's elementwise phase.
    if (MODE == 1 && tid == CTL && t+1 < TS){
      while (__hip_atomic_load(&cnt1[t+1], __ATOMIC_RELAXED, __HIP_MEMORY_SCOPE_AGENT) < NB1)
        __builtin_amdgcn_s_sleep(1);
      __threadfence();
    }

    // ---- dot phase: 4 h-chunk reads, 128 fdot2, accs a0..a7 ----
    const half8* hp = (const half8*)(&hbuf[t & 1][o*40]);
    float a0=0.f,a1=0.f,a2=0.f,a3=0.f,a4=0.f,a5=0.f,a6=0.f,a7=0.f;
#define DOT1(I,C,HV) \
    a##I = __builtin_amdgcn_fdot2(SHUF(w##I##_##C,0,1), SHUF(HV,0,1), a##I, false); \
    a##I = __builtin_amdgcn_fdot2(SHUF(w##I##_##C,2,3), SHUF(HV,2,3), a##I, false); \
    a##I = __builtin_amdgcn_fdot2(SHUF(w##I##_##C,4,5), SHUF(HV,4,5), a##I, false); \
    a##I = __builtin_amdgcn_fdot2(SHUF(w##I##_##C,6,7), SHUF(HV,6,7), a##I, false);
#define DOTCHUNK(C) { half8 hv = hp[C]; \
    DOT1(0,C,hv) DOT1(1,C,hv) DOT1(2,C,hv) DOT1(3,C,hv) \
    DOT1(4,C,hv) DOT1(5,C,hv) DOT1(6,C,hv) DOT1(7,C,hv) }
    DOTCHUNK(0) DOTCHUNK(1) DOTCHUNK(2) DOTCHUNK(3)

    // ---- 8-lane butterfly; lane o ends with full dot of row 8g+o == tid ----
    bool b0 = o & 1, b1 = o & 2, b2 = o & 4;
    float s, r_;
    s = b0 ? a0 : a1; r_ = __shfl_xor(s, 1, 64); float c0 = (b0 ? a1 : a0) + r_;
    s = b0 ? a2 : a3; r_ = __shfl_xor(s, 1, 64); float c1 = (b0 ? a3 : a2) + r_;
    s = b0 ? a4 : a5; r_ = __shfl_xor(s, 1, 64); float c2 = (b0 ? a5 : a4) + r_;
    s = b0 ? a6 : a7; r_ = __shfl_xor(s, 1, 64); float c3 = (b0 ? a7 : a6) + r_;
    s = b1 ? c0 : c1; r_ = __shfl_xor(s, 2, 64); float d0 = (b1 ? c1 : c0) + r_;
    s = b1 ? c2 : c3; r_ = __shfl_xor(s, 2, 64); float d1 = (b1 ? c3 : c2) + r_;
    s = b2 ? d0 : d1; r_ = __shfl_xor(s, 4, 64); float e  = (b2 ? d1 : d0) + r_;
    gh[tid] = e;
    __syncthreads();

    // ---- elementwise phase: unit j = tid < 256 ----
    if (tid < HID){
      float r = sigmoidf_(xr + bh_r + gh[tid]);
      float z = sigmoidf_(xz + bh_z + gh[HID+tid]);
      float n = tanhf_(xn + r*(gh[2*HID+tid] + bh_n));
      float hnew = (1.0f - z)*n + z*hprev;
      hprev = hnew;
      if (MODE == 1) f32out[(long)t*HID + tid] = hnew;
      float partner = __shfl_xor(hnew, 1, 64);
      if ((tid & 1) == 0){
        f16x2 p; p.x = (_Float16)hnew; p.y = (_Float16)partner;
        *(f16x2*)(&hbuf[(t+1)&1][(tid>>5)*40 + (tid&31)]) = p;
        if (MODE == 0) *(f16x2*)(h16out + (long)t*HID + tid) = p;
      }
      if (t+1 < TS){  // prefetch xi[t+1]; latency rides under next dot phase
        const float* xp = xi + (long)(t+1)*G3;
        xr = xp[tid]; xz = xp[HID+tid]; xn = xp[2*HID+tid];
      }
    }
    __syncthreads();
    if (MODE == 0 && tid == CTL){
      __threadfence();   // waitcnt + L2 writeback: covers ALL threads' stores
      __hip_atomic_store(&flag0[t], 1u, __ATOMIC_RELEASE, __HIP_MEMORY_SCOPE_AGENT);
    }
  }
}

__device__ __forceinline__ void xi1_stage(const float* __restrict__ Wih1,
    const float* __restrict__ bih1, const _Float16* __restrict__ h16,
    float* __restrict__ xi1, unsigned* __restrict__ flag0,
    unsigned* __restrict__ cnt1, int slice)
{
  int tid = threadIdx.x;
  int r = tid >> 3, o = tid & 7;        // row r of slice; cols [32o,32o+32)
  int row = slice*RPB + r;
  // weight slice register-resident: 4 half8 = 16 VGPRs (f16)
  half8 w0,w1,w2,w3;
  {
    const float4* wp = (const float4*)(Wih1 + (long)row*HID + o*32);
    float4 p0=wp[0],p1=wp[1],p2=wp[2],p3=wp[3],p4=wp[4],p5=wp[5],p6=wp[6],p7=wp[7];
    w0 = (half8){(_Float16)p0.x,(_Float16)p0.y,(_Float16)p0.z,(_Float16)p0.w,
                 (_Float16)p1.x,(_Float16)p1.y,(_Float16)p1.z,(_Float16)p1.w};
    w1 = (half8){(_Float16)p2.x,(_Float16)p2.y,(_Float16)p2.z,(_Float16)p2.w,
                 (_Float16)p3.x,(_Float16)p3.y,(_Float16)p3.z,(_Float16)p3.w};
    w2 = (half8){(_Float16)p4.x,(_Float16)p4.y,(_Float16)p4.z,(_Float16)p4.w,
                 (_Float16)p5.x,(_Float16)p5.y,(_Float16)p5.z,(_Float16)p5.w};
    w3 = (half8){(_Float16)p6.x,(_Float16)p6.y,(_Float16)p6.z,(_Float16)p6.w,
                 (_Float16)p7.x,(_Float16)p7.y,(_Float16)p7.z,(_Float16)p7.w};
  }
  float bias = bih1[row];

  for (int t = 0; t < TS; t++){
    if (tid == 0){
      while (__hip_atomic_load(&flag0[t], __ATOMIC_RELAXED, __HIP_MEMORY_SCOPE_AGENT) == 0u)
        __builtin_amdgcn_s_sleep(1);
      __threadfence();
    }
    __syncthreads();
    const half8* hp = (const half8*)(h16 + (long)t*HID + o*32);
    half8 h0 = hp[0], h1 = hp[1], h2 = hp[2], h3 = hp[3];
    float acc = 0.f;
#define XDOT(W,H) \
    acc = __builtin_amdgcn_fdot2(SHUF(W,0,1), SHUF(H,0,1), acc, false); \
    acc = __builtin_amdgcn_fdot2(SHUF(W,2,3), SHUF(H,2,3), acc, false); \
    acc = __builtin_amdgcn_fdot2(SHUF(W,4,5), SHUF(H,4,5), acc, false); \
    acc = __builtin_amdgcn_fdot2(SHUF(W,6,7), SHUF(H,6,7), acc, false);
    XDOT(w0,h0) XDOT(w1,h1) XDOT(w2,h2) XDOT(w3,h3)
    acc += __shfl_xor(acc, 1, 64);
    acc += __shfl_xor(acc, 2, 64);
    acc += __shfl_xor(acc, 4, 64);
    if (o == 0) xi1[(long)t*G3 + row] = acc + bias;
    __syncthreads();
    if (tid == 0){
      __threadfence();
      atomicAdd(&cnt1[t], 1u);
    }
  }
}

__global__ __launch_bounds__(768) void pipe_kernel(
    const float* __restrict__ Whh0, const float* __restrict__ bhh0,
    const float* __restrict__ xi0,
    const float* __restrict__ Wih1, const float* __restrict__ bih1,
    const float* __restrict__ Whh1, const float* __restrict__ bhh1,
    _Float16* __restrict__ h1f16, float* __restrict__ xi1,
    float* __restrict__ h2, unsigned* __restrict__ flag0,
    unsigned* __restrict__ cnt1)
{
  __shared__ __align__(16) _Float16 hbuf[2][8*40];
  __shared__ float gh[G3];
  int bid = blockIdx.x;
  if (bid == 0)
    rec_layer<0>(Whh0, bhh0, xi0, h1f16, nullptr, flag0, cnt1, hbuf, gh);
  else if (bid == 9)
    rec_layer<1>(Whh1, bhh1, xi1, nullptr, h2, flag0, cnt1, hbuf, gh);
  else
    xi1_stage(Wih1, bih1, h1f16, xi1, flag0, cnt1, bid - 1);
}

// K5: logits[t][c] = b_out[c] + sum_i h2[t][i] * W_out[c][i]
__global__ __launch_bounds__(1024) void logits_kernel(const float* __restrict__ h2,
    const float* __restrict__ Wout, const float* __restrict__ bout,
    float* __restrict__ out)
{
  __shared__ __align__(16) float wsm[2*HID];
  __shared__ float bs[2];
  int tid = threadIdx.x;
  if (tid < 2*HID) wsm[tid] = Wout[tid];
  if (tid < 2)     bs[tid]  = bout[tid];
  __syncthreads();
  int t = tid >> 1, c = tid & 1;
  const float4* hr = (const float4*)(h2 + (long)t*HID);
  const float4* wr = (const float4*)(wsm + c*HID);
  float acc = bs[c];
  #pragma unroll 8
  for (int m=0;m<HID/4;m++){
    float4 h = hr[m]; float4 wv = wr[m];
    acc += h.x*wv.x + h.y*wv.y + h.z*wv.z + h.w*wv.w;
  }
  out[tid] = acc;
}

extern "C" void kernel_launch(void* const* d_in, const int* in_sizes, int n_in,
                              void* d_out, int out_size, void* d_ws, size_t ws_size,
                              hipStream_t stream)
{
  const int*   x    = (const int*)  d_in[0];
  const float* emb  = (const float*)d_in[1];
  const float* Wih0 = (const float*)d_in[2];
  const float* Whh0 = (const float*)d_in[3];
  const float* bih0 = (const float*)d_in[4];
  const float* bhh0 = (const float*)d_in[5];
  const float* Wih1 = (const float*)d_in[6];
  const float* Whh1 = (const float*)d_in[7];
  const float* bih1 = (const float*)d_in[8];
  const float* bhh1 = (const float*)d_in[9];
  const float* Wout = (const float*)d_in[10];
  const float* bout = (const float*)d_in[11];
  float* out = (float*)d_out;

  char* ws = (char*)d_ws;
  float*     xi0   = (float*)(ws);                       // 512*768 f32 = 1.5 MB
  float*     xi1   = (float*)(ws + 1572864);             // 512*768 f32 = 1.5 MB
  _Float16*  h1f16 = (_Float16*)(ws + 3145728);          // 512*256 f16 = 256 KB
  float*     h2    = (float*)(ws + 3407872);             // 512*256 f32 = 512 KB
  unsigned*  flag0 = (unsigned*)(ws + 3932160);          // 512 u32
  unsigned*  cnt1  = (unsigned*)(ws + 3934208);          // 512 u32

  hipMemsetAsync(ws + 3932160, 0, 4096, stream);
  xi0_kernel<<<64, 256, 0, stream>>>(x, emb, Wih0, bih0, xi0);
  pipe_kernel<<<10, 768, 0, stream>>>(Whh0, bhh0, xi0, Wih1, bih1,
                                      Whh1, bhh1, h1f16, xi1, h2, flag0, cnt1);
  logits_kernel<<<1, 1024, 0, stream>>>(h2, Wout, bout, out);
}

// Round 12
// 901.450 us; speedup vs baseline: 3.2858x; 1.3141x over previous
//
#include <hip/hip_runtime.h>
#include <hip/hip_fp16.h>

typedef _Float16 f16x2 __attribute__((ext_vector_type(2)));
typedef _Float16 half8 __attribute__((ext_vector_type(8)));

#define TS  512
#define HID 256
#define G3  768
#define EMB 128
#define NB1 8
#define RPB 96   // rows per xi1-stage block
#define CTL 767  // poller/publisher thread
#define BSZ 8    // handshake batch (steps)

__device__ __forceinline__ float sigmoidf_(float x){ return 1.0f/(1.0f+__expf(-x)); }
__device__ __forceinline__ float tanhf_(float x){
  float e = __expf(-2.0f*fabsf(x));
  float t = (1.0f-e)/(1.0f+e);
  return copysignf(t,x);
}

// K1: xi0[t][j] = bih0[j] + sum_k Wih0[j][k] * emb[x[t,511]][k]
__global__ __launch_bounds__(256) void xi0_kernel(const int* __restrict__ x,
    const float* __restrict__ emb_tab, const float* __restrict__ Wih0,
    const float* __restrict__ bih0, float* __restrict__ xi0)
{
  __shared__ float embs[8][EMB];
  __shared__ int idx8[8];
  int tid = threadIdx.x;
  int t0  = blockIdx.x * 8;
  if (tid < 8) idx8[tid] = x[(t0 + tid)*512 + 511];
  __syncthreads();
  for (int i = tid; i < 8*EMB; i += 256){
    int q = i >> 7, r = i & 127;
    embs[q][r] = emb_tab[(long)idx8[q]*EMB + r];
  }
  __syncthreads();
  for (int g = 0; g < 3; g++){
    int j = g*256 + tid;
    float b = bih0[j];
    float acc[8];
    #pragma unroll
    for (int u=0;u<8;u++) acc[u]=b;
    const float4* wrow = (const float4*)(Wih0 + (long)j*EMB);
    #pragma unroll 8
    for (int m=0;m<EMB/4;m++){
      float4 w = wrow[m];
      #pragma unroll
      for (int u=0;u<8;u++){
        acc[u] += w.x*embs[u][4*m+0] + w.y*embs[u][4*m+1]
                + w.z*embs[u][4*m+2] + w.w*embs[u][4*m+3];
      }
    }
    #pragma unroll
    for (int u=0;u<8;u++) xi0[(long)(t0+u)*G3 + j] = acc[u];
  }
}

// ---------------- pipelined recurrence (1 kernel, 10 blocks) ----------------
// Handshake is BATCHED by 8 steps (round-12): round-11 showed 4720 cy/step
// with per-step device-scope fences (L2 writeback/invalidate ~1-2k cy each on
// CTL, which the block barrier-waits on). Now: B0 fences + sets flagB[b] once
// per 8 steps; B1..8 wake per batch (one acquire fence, 8 steps of xi1, one
// release fence + atomicAdd cntB[b]); B9 CTL polls cntB only at batch edges.
// Fence cost amortizes 8x; steady-state polls are satisfied instantly since
// producers run ahead (B0 never waits on anyone).
// Recurrence split: thread (g=tid>>3, o=tid&7) owns rows 8g..8g+7 x cols
// [32o,32o+32) -> 64 weight VGPRs + ~20 working ~ the 84 budget.
#define SHUF(V,A,B) __builtin_shufflevector(V,V,A,B)
#define WR32(X) X(0,0) X(0,1) X(0,2) X(0,3) X(1,0) X(1,1) X(1,2) X(1,3) \
                X(2,0) X(2,1) X(2,2) X(2,3) X(3,0) X(3,1) X(3,2) X(3,3) \
                X(4,0) X(4,1) X(4,2) X(4,3) X(5,0) X(5,1) X(5,2) X(5,3) \
                X(6,0) X(6,1) X(6,2) X(6,3) X(7,0) X(7,1) X(7,2) X(7,3)

template<int MODE>  // 0 = producer (layer 1), 1 = consumer (layer 2)
__device__ __forceinline__ void rec_layer(const float* __restrict__ Whh,
    const float* __restrict__ bhh, const float* __restrict__ xi,
    _Float16* __restrict__ h16out, float* __restrict__ f32out,
    unsigned* __restrict__ flagB, unsigned* __restrict__ cntB,
    _Float16 (*hbuf)[8*40], float* gh)
{
  int tid = threadIdx.x;
  int g   = tid >> 3;        // 0..95 : rows 8g..8g+7
  int o   = tid & 7;         // col chunk [32o, 32o+32)

#define WDECL(I,C) half8 w##I##_##C;
  WR32(WDECL)
#define WLOAD(I,C) { \
    const float4* p_ = (const float4*)(Whh + (long)(8*g+(I))*HID + 32*o + 8*(C)); \
    float4 u_ = p_[0], v_ = p_[1]; \
    w##I##_##C = (half8){(_Float16)u_.x,(_Float16)u_.y,(_Float16)u_.z,(_Float16)u_.w, \
                         (_Float16)v_.x,(_Float16)v_.y,(_Float16)v_.z,(_Float16)v_.w}; }
  WR32(WLOAD)

  float bh_r=0.f, bh_z=0.f, bh_n=0.f, hprev=0.f;
  float xr=0.f, xz=0.f, xn=0.f;
  if (tid < HID){
    bh_r = bhh[tid]; bh_z = bhh[HID+tid]; bh_n = bhh[2*HID+tid];
  }
  if (tid < 80) ((half8*)hbuf)[tid] = (half8)(_Float16)0;  // zero both buffers

  if (MODE == 1 && tid == CTL){   // wait for batch 0 of xi1
    while (__hip_atomic_load(&cntB[0], __ATOMIC_RELAXED, __HIP_MEMORY_SCOPE_AGENT) < NB1)
      __builtin_amdgcn_s_sleep(1);
    __threadfence();
  }
  __syncthreads();
  if (tid < HID){  // xi for t=0 (MODE1: safe after cntB[0] confirmed)
    xr = xi[tid]; xz = xi[HID+tid]; xn = xi[2*HID+tid];
  }

  for (int t = 0; t < TS; t++){
    // consumer: at the last step of a batch, confirm the NEXT batch so the
    // elementwise-phase prefetch of xi[t+1] is safe. Runs on CTL concurrent
    // with the dot phase; ordered before prefetch by the post-dot barrier.
    if (MODE == 1 && tid == CTL && ((t+1) & (BSZ-1)) == 0 && t+1 < TS){
      unsigned b = (unsigned)(t+1) >> 3;
      while (__hip_atomic_load(&cntB[b], __ATOMIC_RELAXED, __HIP_MEMORY_SCOPE_AGENT) < NB1)
        __builtin_amdgcn_s_sleep(1);
      __threadfence();
    }

    // ---- dot phase: 4 h-chunk reads, 128 fdot2, accs a0..a7 ----
    const half8* hp = (const half8*)(&hbuf[t & 1][o*40]);
    float a0=0.f,a1=0.f,a2=0.f,a3=0.f,a4=0.f,a5=0.f,a6=0.f,a7=0.f;
#define DOT1(I,C,HV) \
    a##I = __builtin_amdgcn_fdot2(SHUF(w##I##_##C,0,1), SHUF(HV,0,1), a##I, false); \
    a##I = __builtin_amdgcn_fdot2(SHUF(w##I##_##C,2,3), SHUF(HV,2,3), a##I, false); \
    a##I = __builtin_amdgcn_fdot2(SHUF(w##I##_##C,4,5), SHUF(HV,4,5), a##I, false); \
    a##I = __builtin_amdgcn_fdot2(SHUF(w##I##_##C,6,7), SHUF(HV,6,7), a##I, false);
#define DOTCHUNK(C) { half8 hv = hp[C]; \
    DOT1(0,C,hv) DOT1(1,C,hv) DOT1(2,C,hv) DOT1(3,C,hv) \
    DOT1(4,C,hv) DOT1(5,C,hv) DOT1(6,C,hv) DOT1(7,C,hv) }
    DOTCHUNK(0) DOTCHUNK(1) DOTCHUNK(2) DOTCHUNK(3)

    // ---- 8-lane butterfly; lane o ends with full dot of row 8g+o == tid ----
    bool b0 = o & 1, b1 = o & 2, b2 = o & 4;
    float s, r_;
    s = b0 ? a0 : a1; r_ = __shfl_xor(s, 1, 64); float c0 = (b0 ? a1 : a0) + r_;
    s = b0 ? a2 : a3; r_ = __shfl_xor(s, 1, 64); float c1 = (b0 ? a3 : a2) + r_;
    s = b0 ? a4 : a5; r_ = __shfl_xor(s, 1, 64); float c2 = (b0 ? a5 : a4) + r_;
    s = b0 ? a6 : a7; r_ = __shfl_xor(s, 1, 64); float c3 = (b0 ? a7 : a6) + r_;
    s = b1 ? c0 : c1; r_ = __shfl_xor(s, 2, 64); float d0 = (b1 ? c1 : c0) + r_;
    s = b1 ? c2 : c3; r_ = __shfl_xor(s, 2, 64); float d1 = (b1 ? c3 : c2) + r_;
    s = b2 ? d0 : d1; r_ = __shfl_xor(s, 4, 64); float e  = (b2 ? d1 : d0) + r_;
    gh[tid] = e;
    __syncthreads();

    // ---- elementwise phase: unit j = tid < 256 ----
    if (tid < HID){
      float r = sigmoidf_(xr + bh_r + gh[tid]);
      float z = sigmoidf_(xz + bh_z + gh[HID+tid]);
      float n = tanhf_(xn + r*(gh[2*HID+tid] + bh_n));
      float hnew = (1.0f - z)*n + z*hprev;
      hprev = hnew;
      if (MODE == 1) f32out[(long)t*HID + tid] = hnew;
      float partner = __shfl_xor(hnew, 1, 64);
      if ((tid & 1) == 0){
        f16x2 p; p.x = (_Float16)hnew; p.y = (_Float16)partner;
        *(f16x2*)(&hbuf[(t+1)&1][(tid>>5)*40 + (tid&31)]) = p;
        if (MODE == 0) *(f16x2*)(h16out + (long)t*HID + tid) = p;
      }
      if (t+1 < TS){  // prefetch xi[t+1]; latency rides under next dot phase
        const float* xp = xi + (long)(t+1)*G3;
        xr = xp[tid]; xz = xp[HID+tid]; xn = xp[2*HID+tid];
      }
    }
    __syncthreads();
    // producer: publish once per batch (stores of the whole batch precede
    // the barrier above; fence = vmcnt drain + L2 writeback, amortized 8x)
    if (MODE == 0 && tid == CTL && ((t+1) & (BSZ-1)) == 0){
      __threadfence();
      __hip_atomic_store(&flagB[t >> 3], 1u, __ATOMIC_RELEASE, __HIP_MEMORY_SCOPE_AGENT);
    }
  }
}

__device__ __forceinline__ void xi1_stage(const float* __restrict__ Wih1,
    const float* __restrict__ bih1, const _Float16* __restrict__ h16,
    float* __restrict__ xi1, unsigned* __restrict__ flagB,
    unsigned* __restrict__ cntB, int slice)
{
  int tid = threadIdx.x;
  int r = tid >> 3, o = tid & 7;        // row r of slice; cols [32o,32o+32)
  int row = slice*RPB + r;
  half8 w0,w1,w2,w3;                    // 16 VGPRs, register-resident slice
  {
    const float4* wp = (const float4*)(Wih1 + (long)row*HID + o*32);
    float4 p0=wp[0],p1=wp[1],p2=wp[2],p3=wp[3],p4=wp[4],p5=wp[5],p6=wp[6],p7=wp[7];
    w0 = (half8){(_Float16)p0.x,(_Float16)p0.y,(_Float16)p0.z,(_Float16)p0.w,
                 (_Float16)p1.x,(_Float16)p1.y,(_Float16)p1.z,(_Float16)p1.w};
    w1 = (half8){(_Float16)p2.x,(_Float16)p2.y,(_Float16)p2.z,(_Float16)p2.w,
                 (_Float16)p3.x,(_Float16)p3.y,(_Float16)p3.z,(_Float16)p3.w};
    w2 = (half8){(_Float16)p4.x,(_Float16)p4.y,(_Float16)p4.z,(_Float16)p4.w,
                 (_Float16)p5.x,(_Float16)p5.y,(_Float16)p5.z,(_Float16)p5.w};
    w3 = (half8){(_Float16)p6.x,(_Float16)p6.y,(_Float16)p6.z,(_Float16)p6.w,
                 (_Float16)p7.x,(_Float16)p7.y,(_Float16)p7.z,(_Float16)p7.w};
  }
  float bias = bih1[row];

  for (int b = 0; b < TS/BSZ; b++){
    if (tid == 0){
      while (__hip_atomic_load(&flagB[b], __ATOMIC_RELAXED, __HIP_MEMORY_SCOPE_AGENT) == 0u)
        __builtin_amdgcn_s_sleep(1);
      __threadfence();
    }
    __syncthreads();
    #pragma unroll 4
    for (int u = 0; u < BSZ; u++){
      int t = b*BSZ + u;
      const half8* hp = (const half8*)(h16 + (long)t*HID + o*32);
      half8 h0 = hp[0], h1 = hp[1], h2 = hp[2], h3 = hp[3];
      float acc = 0.f;
#define XDOT(W,H) \
      acc = __builtin_amdgcn_fdot2(SHUF(W,0,1), SHUF(H,0,1), acc, false); \
      acc = __builtin_amdgcn_fdot2(SHUF(W,2,3), SHUF(H,2,3), acc, false); \
      acc = __builtin_amdgcn_fdot2(SHUF(W,4,5), SHUF(H,4,5), acc, false); \
      acc = __builtin_amdgcn_fdot2(SHUF(W,6,7), SHUF(H,6,7), acc, false);
      XDOT(w0,h0) XDOT(w1,h1) XDOT(w2,h2) XDOT(w3,h3)
      acc += __shfl_xor(acc, 1, 64);
      acc += __shfl_xor(acc, 2, 64);
      acc += __shfl_xor(acc, 4, 64);
      if (o == 0) xi1[(long)t*G3 + row] = acc + bias;
    }
    __syncthreads();   // drains each thread's stores (vmcnt) before fence
    if (tid == 0){
      __threadfence();
      atomicAdd(&cntB[b], 1u);
    }
  }
}

__global__ __launch_bounds__(768) void pipe_kernel(
    const float* __restrict__ Whh0, const float* __restrict__ bhh0,
    const float* __restrict__ xi0,
    const float* __restrict__ Wih1, const float* __restrict__ bih1,
    const float* __restrict__ Whh1, const float* __restrict__ bhh1,
    _Float16* __restrict__ h1f16, float* __restrict__ xi1,
    float* __restrict__ h2, unsigned* __restrict__ flagB,
    unsigned* __restrict__ cntB)
{
  __shared__ __align__(16) _Float16 hbuf[2][8*40];
  __shared__ float gh[G3];
  int bid = blockIdx.x;
  if (bid == 0)
    rec_layer<0>(Whh0, bhh0, xi0, h1f16, nullptr, flagB, cntB, hbuf, gh);
  else if (bid == 9)
    rec_layer<1>(Whh1, bhh1, xi1, nullptr, h2, flagB, cntB, hbuf, gh);
  else
    xi1_stage(Wih1, bih1, h1f16, xi1, flagB, cntB, bid - 1);
}

// K5: logits[t][c] = b_out[c] + sum_i h2[t][i] * W_out[c][i]
__global__ __launch_bounds__(1024) void logits_kernel(const float* __restrict__ h2,
    const float* __restrict__ Wout, const float* __restrict__ bout,
    float* __restrict__ out)
{
  __shared__ __align__(16) float wsm[2*HID];
  __shared__ float bs[2];
  int tid = threadIdx.x;
  if (tid < 2*HID) wsm[tid] = Wout[tid];
  if (tid < 2)     bs[tid]  = bout[tid];
  __syncthreads();
  int t = tid >> 1, c = tid & 1;
  const float4* hr = (const float4*)(h2 + (long)t*HID);
  const float4* wr = (const float4*)(wsm + c*HID);
  float acc = bs[c];
  #pragma unroll 8
  for (int m=0;m<HID/4;m++){
    float4 h = hr[m]; float4 wv = wr[m];
    acc += h.x*wv.x + h.y*wv.y + h.z*wv.z + h.w*wv.w;
  }
  out[tid] = acc;
}

extern "C" void kernel_launch(void* const* d_in, const int* in_sizes, int n_in,
                              void* d_out, int out_size, void* d_ws, size_t ws_size,
                              hipStream_t stream)
{
  const int*   x    = (const int*)  d_in[0];
  const float* emb  = (const float*)d_in[1];
  const float* Wih0 = (const float*)d_in[2];
  const float* Whh0 = (const float*)d_in[3];
  const float* bih0 = (const float*)d_in[4];
  const float* bhh0 = (const float*)d_in[5];
  const float* Wih1 = (const float*)d_in[6];
  const float* Whh1 = (const float*)d_in[7];
  const float* bih1 = (const float*)d_in[8];
  const float* bhh1 = (const float*)d_in[9];
  const float* Wout = (const float*)d_in[10];
  const float* bout = (const float*)d_in[11];
  float* out = (float*)d_out;

  char* ws = (char*)d_ws;
  float*     xi0   = (float*)(ws);                       // 512*768 f32 = 1.5 MB
  float*     xi1   = (float*)(ws + 1572864);             // 512*768 f32 = 1.5 MB
  _Float16*  h1f16 = (_Float16*)(ws + 3145728);          // 512*256 f16 = 256 KB
  float*     h2    = (float*)(ws + 3407872);             // 512*256 f32 = 512 KB
  unsigned*  flagB = (unsigned*)(ws + 3932160);          // 64 u32
  unsigned*  cntB  = (unsigned*)(ws + 3934208);          // 64 u32

  hipMemsetAsync(ws + 3932160, 0, 4096, stream);
  xi0_kernel<<<64, 256, 0, stream>>>(x, emb, Wih0, bih0, xi0);
  pipe_kernel<<<10, 768, 0, stream>>>(Whh0, bhh0, xi0, Wih1, bih1,
                                      Whh1, bhh1, h1f16, xi1, h2, flagB, cntB);
  logits_kernel<<<1, 1024, 0, stream>>>(h2, Wout, bout, out);
}

// Round 13
// 856.557 us; speedup vs baseline: 3.4581x; 1.0524x over previous
//
#include <hip/hip_runtime.h>
#include <hip/hip_fp16.h>

typedef _Float16 f16x2 __attribute__((ext_vector_type(2)));
typedef _Float16 half8 __attribute__((ext_vector_type(8)));

#define TS  512
#define HID 256
#define G3  768
#define EMB 128
#define NB1 8
#define RPB 96   // rows per xi1-stage block
#define CTL 767  // poller/publisher thread
#define BSZ 8    // handshake batch (steps)

__device__ __forceinline__ float sigmoidf_(float x){ return 1.0f/(1.0f+__expf(-x)); }
__device__ __forceinline__ float tanhf_(float x){
  float e = __expf(-2.0f*fabsf(x));
  float t = (1.0f-e)/(1.0f+e);
  return copysignf(t,x);
}

// K1: xi0[t][j] = bih0[j] + sum_k Wih0[j][k] * emb[x[t,511]][k]
__global__ __launch_bounds__(256) void xi0_kernel(const int* __restrict__ x,
    const float* __restrict__ emb_tab, const float* __restrict__ Wih0,
    const float* __restrict__ bih0, float* __restrict__ xi0)
{
  __shared__ float embs[8][EMB];
  __shared__ int idx8[8];
  int tid = threadIdx.x;
  int t0  = blockIdx.x * 8;
  if (tid < 8) idx8[tid] = x[(t0 + tid)*512 + 511];
  __syncthreads();
  for (int i = tid; i < 8*EMB; i += 256){
    int q = i >> 7, r = i & 127;
    embs[q][r] = emb_tab[(long)idx8[q]*EMB + r];
  }
  __syncthreads();
  for (int g = 0; g < 3; g++){
    int j = g*256 + tid;
    float b = bih0[j];
    float acc[8];
    #pragma unroll
    for (int u=0;u<8;u++) acc[u]=b;
    const float4* wrow = (const float4*)(Wih0 + (long)j*EMB);
    #pragma unroll 8
    for (int m=0;m<EMB/4;m++){
      float4 w = wrow[m];
      #pragma unroll
      for (int u=0;u<8;u++){
        acc[u] += w.x*embs[u][4*m+0] + w.y*embs[u][4*m+1]
                + w.z*embs[u][4*m+2] + w.w*embs[u][4*m+3];
      }
    }
    #pragma unroll
    for (int u=0;u<8;u++) xi0[(long)(t0+u)*G3 + j] = acc[u];
  }
}

// ---------------- pipelined recurrence (1 kernel, 10 blocks) ----------------
// ROUND-13: round-12 measured 3600 cy/step in the rec blocks. Root cause
// finally quantified: full weight residency needs 512 B/thread = 128 VGPRs
// (NOT 64 — a half8 is 4 regs), demand ~150 vs the 84-reg budget the
// compiler grants (half the RF per workgroup, immune to every attribute
// tried in rounds 1-12). Spill reload = 198 KB/step through scratch-L2
// @ ~60 B/cy = 3300 cy — the measured wall (VALU-busy model matches 0.69%).
// Fix attempt: amdgpu_max_num_work_groups(10,1,1) — declares the TRUE grid
// (10 blocks over 256 CUs -> provably <=1 wg/CU), which the LLVM occupancy
// heuristic can use to lift the budget to the launch_bounds(768,3) cap
// (~170 regs). Zero correctness risk (value is the real grid). If honored:
// zero spill, step -> ~1300 cy. Tell: VGPR_Count 84 -> ~150+.
#define SHUF(V,A,B) __builtin_shufflevector(V,V,A,B)
#define WR32(X) X(0,0) X(0,1) X(0,2) X(0,3) X(1,0) X(1,1) X(1,2) X(1,3) \
                X(2,0) X(2,1) X(2,2) X(2,3) X(3,0) X(3,1) X(3,2) X(3,3) \
                X(4,0) X(4,1) X(4,2) X(4,3) X(5,0) X(5,1) X(5,2) X(5,3) \
                X(6,0) X(6,1) X(6,2) X(6,3) X(7,0) X(7,1) X(7,2) X(7,3)

template<int MODE>  // 0 = producer (layer 1), 1 = consumer (layer 2)
__device__ __forceinline__ void rec_layer(const float* __restrict__ Whh,
    const float* __restrict__ bhh, const float* __restrict__ xi,
    _Float16* __restrict__ h16out, float* __restrict__ f32out,
    unsigned* __restrict__ flagB, unsigned* __restrict__ cntB,
    _Float16 (*hbuf)[8*40], float* gh, float* bhhL)
{
  int tid = threadIdx.x;
  int g   = tid >> 3;        // 0..95 : rows 8g..8g+7
  int o   = tid & 7;         // col chunk [32o, 32o+32)

#define WDECL(I,C) half8 w##I##_##C;
  WR32(WDECL)
#define WLOAD(I,C) { \
    const float4* p_ = (const float4*)(Whh + (long)(8*g+(I))*HID + 32*o + 8*(C)); \
    float4 u_ = p_[0], v_ = p_[1]; \
    w##I##_##C = (half8){(_Float16)u_.x,(_Float16)u_.y,(_Float16)u_.z,(_Float16)u_.w, \
                         (_Float16)v_.x,(_Float16)v_.y,(_Float16)v_.z,(_Float16)v_.w}; }
  WR32(WLOAD)

  float hprev = 0.f;
  float xr=0.f, xz=0.f, xn=0.f;
  bhhL[tid] = bhh[tid];                       // biases live in LDS (3 regs saved)
  if (tid < 80) ((half8*)hbuf)[tid] = (half8)(_Float16)0;  // zero both buffers

  if (MODE == 1 && tid == CTL){   // wait for batch 0 of xi1
    while (__hip_atomic_load(&cntB[0], __ATOMIC_RELAXED, __HIP_MEMORY_SCOPE_AGENT) < NB1)
      __builtin_amdgcn_s_sleep(1);
    __threadfence();
  }
  __syncthreads();
  if (tid < HID){  // xi for t=0 (MODE1: safe after cntB[0] confirmed)
    xr = xi[tid]; xz = xi[HID+tid]; xn = xi[2*HID+tid];
  }

  for (int t = 0; t < TS; t++){
    // consumer: at the last step of a batch, confirm the NEXT batch so the
    // elementwise-phase prefetch of xi[t+1] is safe.
    if (MODE == 1 && tid == CTL && ((t+1) & (BSZ-1)) == 0 && t+1 < TS){
      unsigned b = (unsigned)(t+1) >> 3;
      while (__hip_atomic_load(&cntB[b], __ATOMIC_RELAXED, __HIP_MEMORY_SCOPE_AGENT) < NB1)
        __builtin_amdgcn_s_sleep(1);
      __threadfence();
    }

    // ---- dot phase: 4 h-chunk reads, 128 fdot2, accs a0..a7 ----
    const half8* hp = (const half8*)(&hbuf[t & 1][o*40]);
    float a0=0.f,a1=0.f,a2=0.f,a3=0.f,a4=0.f,a5=0.f,a6=0.f,a7=0.f;
#define DOT1(I,C,HV) \
    a##I = __builtin_amdgcn_fdot2(SHUF(w##I##_##C,0,1), SHUF(HV,0,1), a##I, false); \
    a##I = __builtin_amdgcn_fdot2(SHUF(w##I##_##C,2,3), SHUF(HV,2,3), a##I, false); \
    a##I = __builtin_amdgcn_fdot2(SHUF(w##I##_##C,4,5), SHUF(HV,4,5), a##I, false); \
    a##I = __builtin_amdgcn_fdot2(SHUF(w##I##_##C,6,7), SHUF(HV,6,7), a##I, false);
#define DOTCHUNK(C) { half8 hv = hp[C]; \
    DOT1(0,C,hv) DOT1(1,C,hv) DOT1(2,C,hv) DOT1(3,C,hv) \
    DOT1(4,C,hv) DOT1(5,C,hv) DOT1(6,C,hv) DOT1(7,C,hv) }
    DOTCHUNK(0) DOTCHUNK(1) DOTCHUNK(2) DOTCHUNK(3)

    // ---- 8-lane butterfly; lane o ends with full dot of row 8g+o == tid ----
    bool b0 = o & 1, b1 = o & 2, b2 = o & 4;
    float s, r_;
    s = b0 ? a0 : a1; r_ = __shfl_xor(s, 1, 64); float c0 = (b0 ? a1 : a0) + r_;
    s = b0 ? a2 : a3; r_ = __shfl_xor(s, 1, 64); float c1 = (b0 ? a3 : a2) + r_;
    s = b0 ? a4 : a5; r_ = __shfl_xor(s, 1, 64); float c2 = (b0 ? a5 : a4) + r_;
    s = b0 ? a6 : a7; r_ = __shfl_xor(s, 1, 64); float c3 = (b0 ? a7 : a6) + r_;
    s = b1 ? c0 : c1; r_ = __shfl_xor(s, 2, 64); float d0 = (b1 ? c1 : c0) + r_;
    s = b1 ? c2 : c3; r_ = __shfl_xor(s, 2, 64); float d1 = (b1 ? c3 : c2) + r_;
    s = b2 ? d0 : d1; r_ = __shfl_xor(s, 4, 64); float e  = (b2 ? d1 : d0) + r_;
    gh[tid] = e;
    __syncthreads();

    // ---- elementwise phase: unit j = tid < 256 ----
    if (tid < HID){
      float r = sigmoidf_(xr + bhhL[tid] + gh[tid]);
      float z = sigmoidf_(xz + bhhL[HID+tid] + gh[HID+tid]);
      float n = tanhf_(xn + r*(gh[2*HID+tid] + bhhL[2*HID+tid]));
      float hnew = (1.0f - z)*n + z*hprev;
      hprev = hnew;
      if (MODE == 1) f32out[(long)t*HID + tid] = hnew;
      float partner = __shfl_xor(hnew, 1, 64);
      if ((tid & 1) == 0){
        f16x2 p; p.x = (_Float16)hnew; p.y = (_Float16)partner;
        *(f16x2*)(&hbuf[(t+1)&1][(tid>>5)*40 + (tid&31)]) = p;
        if (MODE == 0) *(f16x2*)(h16out + (long)t*HID + tid) = p;
      }
      if (t+1 < TS){  // prefetch xi[t+1]; latency rides under next dot phase
        const float* xp = xi + (long)(t+1)*G3;
        xr = xp[tid]; xz = xp[HID+tid]; xn = xp[2*HID+tid];
      }
    }
    __syncthreads();
    // producer: publish once per batch
    if (MODE == 0 && tid == CTL && ((t+1) & (BSZ-1)) == 0){
      __threadfence();
      __hip_atomic_store(&flagB[t >> 3], 1u, __ATOMIC_RELEASE, __HIP_MEMORY_SCOPE_AGENT);
    }
  }
}

__device__ __forceinline__ void xi1_stage(const float* __restrict__ Wih1,
    const float* __restrict__ bih1, const _Float16* __restrict__ h16,
    float* __restrict__ xi1, unsigned* __restrict__ flagB,
    unsigned* __restrict__ cntB, int slice)
{
  int tid = threadIdx.x;
  int r = tid >> 3, o = tid & 7;        // row r of slice; cols [32o,32o+32)
  int row = slice*RPB + r;
  half8 w0,w1,w2,w3;                    // 16 VGPRs, register-resident slice
  {
    const float4* wp = (const float4*)(Wih1 + (long)row*HID + o*32);
    float4 p0=wp[0],p1=wp[1],p2=wp[2],p3=wp[3],p4=wp[4],p5=wp[5],p6=wp[6],p7=wp[7];
    w0 = (half8){(_Float16)p0.x,(_Float16)p0.y,(_Float16)p0.z,(_Float16)p0.w,
                 (_Float16)p1.x,(_Float16)p1.y,(_Float16)p1.z,(_Float16)p1.w};
    w1 = (half8){(_Float16)p2.x,(_Float16)p2.y,(_Float16)p2.z,(_Float16)p2.w,
                 (_Float16)p3.x,(_Float16)p3.y,(_Float16)p3.z,(_Float16)p3.w};
    w2 = (half8){(_Float16)p4.x,(_Float16)p4.y,(_Float16)p4.z,(_Float16)p4.w,
                 (_Float16)p5.x,(_Float16)p5.y,(_Float16)p5.z,(_Float16)p5.w};
    w3 = (half8){(_Float16)p6.x,(_Float16)p6.y,(_Float16)p6.z,(_Float16)p6.w,
                 (_Float16)p7.x,(_Float16)p7.y,(_Float16)p7.z,(_Float16)p7.w};
  }
  float bias = bih1[row];

  for (int b = 0; b < TS/BSZ; b++){
    if (tid == 0){
      while (__hip_atomic_load(&flagB[b], __ATOMIC_RELAXED, __HIP_MEMORY_SCOPE_AGENT) == 0u)
        __builtin_amdgcn_s_sleep(1);
      __threadfence();
    }
    __syncthreads();
    #pragma unroll 4
    for (int u = 0; u < BSZ; u++){
      int t = b*BSZ + u;
      const half8* hp = (const half8*)(h16 + (long)t*HID + o*32);
      half8 h0 = hp[0], h1 = hp[1], h2 = hp[2], h3 = hp[3];
      float acc = 0.f;
#define XDOT(W,H) \
      acc = __builtin_amdgcn_fdot2(SHUF(W,0,1), SHUF(H,0,1), acc, false); \
      acc = __builtin_amdgcn_fdot2(SHUF(W,2,3), SHUF(H,2,3), acc, false); \
      acc = __builtin_amdgcn_fdot2(SHUF(W,4,5), SHUF(H,4,5), acc, false); \
      acc = __builtin_amdgcn_fdot2(SHUF(W,6,7), SHUF(H,6,7), acc, false);
      XDOT(w0,h0) XDOT(w1,h1) XDOT(w2,h2) XDOT(w3,h3)
      acc += __shfl_xor(acc, 1, 64);
      acc += __shfl_xor(acc, 2, 64);
      acc += __shfl_xor(acc, 4, 64);
      if (o == 0) xi1[(long)t*G3 + row] = acc + bias;
    }
    __syncthreads();   // drains each thread's stores (vmcnt) before fence
    if (tid == 0){
      __threadfence();
      atomicAdd(&cntB[b], 1u);
    }
  }
}

__global__ __launch_bounds__(768, 3)
__attribute__((amdgpu_max_num_work_groups(10, 1, 1)))
void pipe_kernel(
    const float* __restrict__ Whh0, const float* __restrict__ bhh0,
    const float* __restrict__ xi0,
    const float* __restrict__ Wih1, const float* __restrict__ bih1,
    const float* __restrict__ Whh1, const float* __restrict__ bhh1,
    _Float16* __restrict__ h1f16, float* __restrict__ xi1,
    float* __restrict__ h2, unsigned* __restrict__ flagB,
    unsigned* __restrict__ cntB)
{
  __shared__ __align__(16) _Float16 hbuf[2][8*40];
  __shared__ float gh[G3];
  __shared__ float bhhL[G3];
  int bid = blockIdx.x;
  if (bid == 0)
    rec_layer<0>(Whh0, bhh0, xi0, h1f16, nullptr, flagB, cntB, hbuf, gh, bhhL);
  else if (bid == 9)
    rec_layer<1>(Whh1, bhh1, xi1, nullptr, h2, flagB, cntB, hbuf, gh, bhhL);
  else
    xi1_stage(Wih1, bih1, h1f16, xi1, flagB, cntB, bid - 1);
}

// K5: logits[t][c] = b_out[c] + sum_i h2[t][i] * W_out[c][i]
__global__ __launch_bounds__(1024) void logits_kernel(const float* __restrict__ h2,
    const float* __restrict__ Wout, const float* __restrict__ bout,
    float* __restrict__ out)
{
  __shared__ __align__(16) float wsm[2*HID];
  __shared__ float bs[2];
  int tid = threadIdx.x;
  if (tid < 2*HID) wsm[tid] = Wout[tid];
  if (tid < 2)     bs[tid]  = bout[tid];
  __syncthreads();
  int t = tid >> 1, c = tid & 1;
  const float4* hr = (const float4*)(h2 + (long)t*HID);
  const float4* wr = (const float4*)(wsm + c*HID);
  float acc = bs[c];
  #pragma unroll 8
  for (int m=0;m<HID/4;m++){
    float4 h = hr[m]; float4 wv = wr[m];
    acc += h.x*wv.x + h.y*wv.y + h.z*wv.z + h.w*wv.w;
  }
  out[tid] = acc;
}

extern "C" void kernel_launch(void* const* d_in, const int* in_sizes, int n_in,
                              void* d_out, int out_size, void* d_ws, size_t ws_size,
                              hipStream_t stream)
{
  const int*   x    = (const int*)  d_in[0];
  const float* emb  = (const float*)d_in[1];
  const float* Wih0 = (const float*)d_in[2];
  const float* Whh0 = (const float*)d_in[3];
  const float* bih0 = (const float*)d_in[4];
  const float* bhh0 = (const float*)d_in[5];
  const float* Wih1 = (const float*)d_in[6];
  const float* Whh1 = (const float*)d_in[7];
  const float* bih1 = (const float*)d_in[8];
  const float* bhh1 = (const float*)d_in[9];
  const float* Wout = (const float*)d_in[10];
  const float* bout = (const float*)d_in[11];
  float* out = (float*)d_out;

  char* ws = (char*)d_ws;
  float*     xi0   = (float*)(ws);                       // 512*768 f32 = 1.5 MB
  float*     xi1   = (float*)(ws + 1572864);             // 512*768 f32 = 1.5 MB
  _Float16*  h1f16 = (_Float16*)(ws + 3145728);          // 512*256 f16 = 256 KB
  float*     h2    = (float*)(ws + 3407872);             // 512*256 f32 = 512 KB
  unsigned*  flagB = (unsigned*)(ws + 3932160);          // 64 u32
  unsigned*  cntB  = (unsigned*)(ws + 3934208);          // 64 u32

  hipMemsetAsync(ws + 3932160, 0, 4096, stream);
  xi0_kernel<<<64, 256, 0, stream>>>(x, emb, Wih0, bih0, xi0);
  pipe_kernel<<<10, 768, 0, stream>>>(Whh0, bhh0, xi0, Wih1, bih1,
                                      Whh1, bhh1, h1f16, xi1, h2, flagB, cntB);
  logits_kernel<<<1, 1024, 0, stream>>>(h2, Wout, bout, out);
}